// Round 11
// baseline (153.773 us; speedup 1.0000x reference)
//
#include <hip/hip_runtime.h>
#include <hip/hip_bf16.h>
#include <type_traits>

// Dims: B=8, L=2048, T=1024, Dh=1024, Dg=768, Dp=256
// Pipeline: HT=transpose(H); Q=G@Wq^T; K=H@Wk^T; Sexp=exp(Q@K^T/16)[+rowsum];
//           Z=(Sexp@HT^T)/rowsum
// R11: attention GEMMs -> 128x128/BK=32/16KB-LDS/8-wave m97 loop (TLP-first:
//      2 blocks/CU for PV, vs 1 big block before). Direct epilogues.
// Workspace (u16): Qbf 2M | Kbf 4M | HT 16M | S 16M | rowsum f32 B*T

typedef float    f32x4  __attribute__((ext_vector_type(4)));
typedef __bf16   bf16x8 __attribute__((ext_vector_type(8)));
typedef unsigned short u16x8 __attribute__((ext_vector_type(8)));

__device__ __forceinline__ unsigned short f2bf(float f) {
    union { float f; unsigned u; } x; x.f = f;
    return (unsigned short)((x.u + 0x7fffu + ((x.u >> 16) & 1u)) >> 16);
}
__device__ __forceinline__ float bf2f(unsigned short u) {
    union { unsigned u; float f; } x; x.u = ((unsigned)u) << 16;
    return x.f;
}
__device__ __forceinline__ void gload_lds16(const unsigned short* g, unsigned short* l) {
    __builtin_amdgcn_global_load_lds(
        (const __attribute__((address_space(1))) void*)g,
        (__attribute__((address_space(3))) void*)l, 16, 0, 0);
}

// ---------------- transpose: H [L,Dh] f32 -> HT [Dh,L] bf16; 64x64 tiles ----------------
__global__ __launch_bounds__(256) void kn_transp(const float* __restrict__ H,
                                                 unsigned short* __restrict__ HT,
                                                 int L, int D) {
    __shared__ float tile[64][65];
    int b = blockIdx.z;
    const float* src = H + (size_t)b * L * D;
    unsigned short* dstT = HT + (size_t)b * L * D;
    int l0 = blockIdx.y * 64, d0 = blockIdx.x * 64;
    int tx = threadIdx.x, ty = threadIdx.y;
#pragma unroll
    for (int i = ty; i < 64; i += 4)
        tile[i][tx] = src[(size_t)(l0 + i) * D + d0 + tx];
    __syncthreads();
#pragma unroll
    for (int i = ty; i < 64; i += 4)
        dstT[(size_t)(d0 + i) * L + l0 + tx] = f2bf(tile[tx][i]);
}

// -------- projection: C[M,N]=A[M,K]@B^T[N,K], f32 in, bf16 out; TM x 128 tile --------
template<int TM, int WM>
__device__ __forceinline__ void proj_body(const float* __restrict__ A,
                                          const float* __restrict__ B,
                                          unsigned short* __restrict__ C,
                                          int N, int K, int gxs) {
    constexpr int WN  = 4 / WM;
    constexpr int MF  = (TM / WM) / 16;
    constexpr int NF  = (128 / WN) / 16;
    constexpr int CHA = TM * 8;
    constexpr int CHT = CHA + 1024;
    constexpr int CPT = CHT / 256;
    constexpr int BUFU = TM * 64 + 128 * 64;
    constexpr int LDSB = (2 * BUFU * 2 > TM * 132 * 4) ? 2 * BUFU * 2 : TM * 132 * 4;
    __shared__ __align__(16) char smem_raw[LDSB];
    unsigned short* base = (unsigned short*)smem_raw;
    float* st = (float*)smem_raw;

    int tid = threadIdx.x;
    int t = blockIdx.x;
    int by = t >> gxs;
    int bx = t & ((1 << gxs) - 1);
    const float* Ab = A + (size_t)by * TM * K;
    const float* Bb = B + (size_t)bx * 128 * K;

    int lane = tid & 63;
    int wid = tid >> 6;
    int wr = wid / WN, wc = wid % WN;
    int lr = lane & 15;
    int lg = lane >> 4;
    int xoff = (lane & 7) << 3;

    f32x4 rv[CPT][2];
    f32x4 acc[MF][NF] = {};

    auto LOAD = [&](int k0) {
#pragma unroll
        for (int c = 0; c < CPT; ++c) {
            int ch = c * 256 + tid;
            const float* src;
            if (ch < CHA) {
                int row = ch >> 3;
                src = Ab + (size_t)row * K + k0 + (ch & 7) * 8;
            } else {
                int bc = ch - CHA;
                int row = bc >> 3;
                src = Bb + (size_t)row * K + k0 + (bc & 7) * 8;
            }
            rv[c][0] = *(const f32x4*)src;
            rv[c][1] = *(const f32x4*)(src + 4);
        }
    };
    auto WRITE = [&](int buf) {
        unsigned short* dA = base + buf * BUFU;
        unsigned short* dB = dA + TM * 64;
#pragma unroll
        for (int c = 0; c < CPT; ++c) {
            int ch = c * 256 + tid;
            u16x8 o;
#pragma unroll
            for (int j = 0; j < 4; ++j) { o[j] = f2bf(rv[c][0][j]); o[4 + j] = f2bf(rv[c][1][j]); }
            if (ch < CHA) {
                int row = ch >> 3;
                int sl = (ch & 7) ^ (row & 7);
                *(u16x8*)&dA[row * 64 + sl * 8] = o;
            } else {
                int bc = ch - CHA;
                int row = bc >> 3;
                int sl = (bc & 7) ^ (row & 7);
                *(u16x8*)&dB[row * 64 + sl * 8] = o;
            }
        }
    };
    auto COMPUTE = [&](int buf) {
        unsigned short* pA = base + buf * BUFU;
        unsigned short* pB = pA + TM * 64;
#pragma unroll
        for (int kk = 0; kk < 2; ++kk) {
            int kb = (kk * 32 + lg * 8) ^ xoff;
            bf16x8 af[MF], bfr[NF];
#pragma unroll
            for (int m = 0; m < MF; ++m)
                af[m] = *(const bf16x8*)&pA[(wr * MF * 16 + m * 16 + lr) * 64 + kb];
#pragma unroll
            for (int n = 0; n < NF; ++n)
                bfr[n] = *(const bf16x8*)&pB[(wc * NF * 16 + n * 16 + lr) * 64 + kb];
#pragma unroll
            for (int m = 0; m < MF; ++m)
#pragma unroll
                for (int n = 0; n < NF; ++n)
                    acc[m][n] = __builtin_amdgcn_mfma_f32_16x16x32_bf16(af[m], bfr[n], acc[m][n], 0, 0, 0);
        }
    };

    int nt = K / 64;
    LOAD(0);
    WRITE(0);
    __syncthreads();
    int buf = 0;
    for (int tt = 0; tt < nt; ++tt) {
        if (tt + 1 < nt) LOAD((tt + 1) * 64);
        COMPUTE(buf);
        if (tt + 1 < nt) WRITE(buf ^ 1);
        __syncthreads();
        buf ^= 1;
    }

#pragma unroll
    for (int m = 0; m < MF; ++m) {
        int r0 = wr * MF * 16 + m * 16 + lg * 4;
#pragma unroll
        for (int n = 0; n < NF; ++n) {
            int c0 = wc * NF * 16 + n * 16 + lr;
#pragma unroll
            for (int j = 0; j < 4; ++j)
                st[(r0 + j) * 132 + c0] = acc[m][n][j];
        }
    }
    __syncthreads();
    constexpr int TPR = 256 / TM;
    constexpr int CW  = 128 / TPR;
    int r  = tid / TPR;
    int c0 = (tid % TPR) * CW;
    size_t grow = (size_t)(by * TM + r) * N + bx * 128 + c0;
#pragma unroll
    for (int g = 0; g < CW / 8; ++g) {
        f32x4 a = *(const f32x4*)&st[r * 132 + c0 + g * 8];
        f32x4 b = *(const f32x4*)&st[r * 132 + c0 + g * 8 + 4];
        u16x8 o;
#pragma unroll
        for (int j = 0; j < 4; ++j) { o[j] = f2bf(a[j]); o[4 + j] = f2bf(b[j]); }
        *(u16x8*)&C[grow + g * 8] = o;
    }
}

__global__ __launch_bounds__(256) void kn_qproj(const float* A, const float* B,
                                                unsigned short* C, int N, int K, int gxs) {
    proj_body<32, 1>(A, B, C, N, K, gxs);
}
__global__ __launch_bounds__(256) void kn_kproj(const float* A, const float* B,
                                                unsigned short* C, int N, int K, int gxs) {
    proj_body<64, 2>(A, B, C, N, K, gxs);
}

// ======== 128x128 / BK=32 / 16KB-LDS / 8-wave (4M x 2N) m97-style loop ========
// Per thread: 2 gload_lds chunks/step. Per wave/step: 2 A-frags + 4 B-frags, 8 MFMA.
// Wave-tile 32x64. acc[2][4]. No swizzle (m97-tolerated conflicts), direct epilogue.

__device__ __forceinline__ void stage128(const unsigned short* Ab, const unsigned short* Bb,
                                         int K, int k0, unsigned short* sA, unsigned short* sB,
                                         int tid) {
#pragma unroll
    for (int c = 0; c < 2; ++c) {
        int ch = c * 512 + tid;               // 0..1023
        if (ch < 512) {
            int row = ch >> 2;
            gload_lds16(Ab + (size_t)row * K + k0 + (ch & 3) * 8, sA + ch * 8);
        } else {
            int bc = ch - 512;
            int row = bc >> 2;
            gload_lds16(Bb + (size_t)row * K + k0 + (bc & 3) * 8, sB + bc * 8);
        }
    }
}

// ---- S-GEMM: Sexp[b] = exp(Q@K^T/16), rowsum atomics ----
__global__ __launch_bounds__(512) void kn_sgemm(const unsigned short* __restrict__ A,
                                                const unsigned short* __restrict__ B,
                                                unsigned short* __restrict__ C,
                                                float* __restrict__ rowsum,
                                                int N, int K, int Trows,
                                                long batchA, long batchB, long batchC,
                                                float scale, int gxs) {
    __shared__ __align__(16) unsigned short sA[128 * 32];
    __shared__ __align__(16) unsigned short sB[128 * 32];

    int tid = threadIdx.x;
    int wg = blockIdx.x;
    int bz = wg & 7;
    int t = wg >> 3;
    int by = t >> gxs;
    int bx = t & ((1 << gxs) - 1);

    const unsigned short* Ab = A + (size_t)bz * batchA + (size_t)by * 128 * K;
    const unsigned short* Bb = B + (size_t)bz * batchB + (size_t)bx * 128 * K;
    unsigned short* Cb = C + (size_t)bz * batchC;
    float* rs = rowsum + (size_t)bz * Trows;

    int lane = tid & 63;
    int wid = tid >> 6;
    int wr = wid >> 1, wc = wid & 1;      // 4M x 2N
    int lr = lane & 15;
    int lg = lane >> 4;

    f32x4 acc[2][4] = {};

    for (int k0 = 0; k0 < K; k0 += 32) {
        stage128(Ab, Bb, K, k0, sA, sB, tid);
        __syncthreads();
        bf16x8 af[2], bfr[4];
#pragma unroll
        for (int m = 0; m < 2; ++m)
            af[m] = *(const bf16x8*)&sA[(wr * 32 + m * 16 + lr) * 32 + lg * 8];
#pragma unroll
        for (int n = 0; n < 4; ++n)
            bfr[n] = *(const bf16x8*)&sB[(wc * 64 + n * 16 + lr) * 32 + lg * 8];
#pragma unroll
        for (int m = 0; m < 2; ++m)
#pragma unroll
            for (int n = 0; n < 4; ++n)
                acc[m][n] = __builtin_amdgcn_mfma_f32_16x16x32_bf16(af[m], bfr[n], acc[m][n], 0, 0, 0);
        __syncthreads();
    }

    // epilogue: exp + bf16 store + rowsum atomics
    float psum[2][4] = {};
#pragma unroll
    for (int m = 0; m < 2; ++m) {
#pragma unroll
        for (int j = 0; j < 4; ++j) {
            int row = by * 128 + wr * 32 + m * 16 + lg * 4 + j;
#pragma unroll
            for (int n = 0; n < 4; ++n) {
                int col = bx * 128 + wc * 64 + n * 16 + lr;
                unsigned short ov = f2bf(__expf(acc[m][n][j] * scale));
                Cb[(size_t)row * N + col] = ov;
                psum[m][j] += bf2f(ov);
            }
        }
    }
#pragma unroll
    for (int m = 0; m < 2; ++m)
#pragma unroll
        for (int j = 0; j < 4; ++j) {
            float s = psum[m][j];
            s += __shfl_xor(s, 1);
            s += __shfl_xor(s, 2);
            s += __shfl_xor(s, 4);
            s += __shfl_xor(s, 8);
            if (lr == 0)
                atomicAdd(&rs[by * 128 + wr * 32 + m * 16 + lg * 4 + j], s);
        }
}

// ---- PV: Z[b] = (Sexp @ HT^T) / rowsum ----
__global__ __launch_bounds__(512) void kn_pv(const unsigned short* __restrict__ A,
                                             const unsigned short* __restrict__ B,
                                             float* __restrict__ C,
                                             const float* __restrict__ rowsum,
                                             int N, int K, int Trows,
                                             long batchA, long batchB, long batchC,
                                             int gxs) {
    __shared__ __align__(16) unsigned short sA[128 * 32];
    __shared__ __align__(16) unsigned short sB[128 * 32];

    int tid = threadIdx.x;
    int wg = blockIdx.x;
    int bz = wg & 7;
    int t = wg >> 3;
    int by = t >> gxs;
    int bx = t & ((1 << gxs) - 1);

    const unsigned short* Ab = A + (size_t)bz * batchA + (size_t)by * 128 * K;
    const unsigned short* Bb = B + (size_t)bz * batchB + (size_t)bx * 128 * K;
    float* Cb = C + (size_t)bz * batchC;
    const float* rs = rowsum + (size_t)bz * Trows;

    int lane = tid & 63;
    int wid = tid >> 6;
    int wr = wid >> 1, wc = wid & 1;      // 4M x 2N
    int lr = lane & 15;
    int lg = lane >> 4;

    f32x4 acc[2][4] = {};

    for (int k0 = 0; k0 < K; k0 += 32) {
        stage128(Ab, Bb, K, k0, sA, sB, tid);
        __syncthreads();
        bf16x8 af[2], bfr[4];
#pragma unroll
        for (int m = 0; m < 2; ++m)
            af[m] = *(const bf16x8*)&sA[(wr * 32 + m * 16 + lr) * 32 + lg * 8];
#pragma unroll
        for (int n = 0; n < 4; ++n)
            bfr[n] = *(const bf16x8*)&sB[(wc * 64 + n * 16 + lr) * 32 + lg * 8];
#pragma unroll
        for (int m = 0; m < 2; ++m)
#pragma unroll
            for (int n = 0; n < 4; ++n)
                acc[m][n] = __builtin_amdgcn_mfma_f32_16x16x32_bf16(af[m], bfr[n], acc[m][n], 0, 0, 0);
        __syncthreads();
    }

    // epilogue: divide by rowsum, direct f32 stores
#pragma unroll
    for (int m = 0; m < 2; ++m) {
#pragma unroll
        for (int j = 0; j < 4; ++j) {
            int rloc = by * 128 + wr * 32 + m * 16 + lg * 4 + j;
            float inv = 1.0f / rs[rloc];
#pragma unroll
            for (int n = 0; n < 4; ++n) {
                int col = bx * 128 + wc * 64 + n * 16 + lr;
                Cb[(size_t)rloc * N + col] = acc[m][n][j] * inv;
            }
        }
    }
}

extern "C" void kernel_launch(void* const* d_in, const int* in_sizes, int n_in,
                              void* d_out, int out_size, void* d_ws, size_t ws_size,
                              hipStream_t stream) {
    constexpr int B = 8, L = 2048, T = 1024, Dh = 1024, Dg = 768, Dp = 256;
    const float* H  = (const float*)d_in[0];
    const float* G  = (const float*)d_in[1];
    const float* Wq = (const float*)d_in[2];
    const float* Wk = (const float*)d_in[3];
    float* Z = (float*)d_out;

    unsigned short* Qbf = (unsigned short*)d_ws;             // B*T*Dp  = 2M
    unsigned short* Kbf = Qbf + (size_t)B * T * Dp;          // B*L*Dp  = 4M
    unsigned short* HT  = Kbf + (size_t)B * L * Dp;          // B*Dh*L  = 16M
    unsigned short* S   = HT  + (size_t)B * Dh * L;          // B*T*L   = 16M
    float* rowsum = (float*)(S + (size_t)B * T * L);         // B*T f32

    hipMemsetAsync(rowsum, 0, (size_t)B * T * sizeof(float), stream);

    kn_transp<<<dim3(Dh / 64, L / 64, B), dim3(64, 4), 0, stream>>>(H, HT, L, Dh);

    kn_qproj<<<(B * T / 32) * (Dp / 128), 256, 0, stream>>>(G, Wq, Qbf, Dp, Dg, 1);

    kn_kproj<<<(B * L / 64) * (Dp / 128), 256, 0, stream>>>(H, Wk, Kbf, Dp, Dh, 1);

    // Sexp[b] = exp(Q@K^T/16): [1024 x 2048], 128^2 tiles -> 8*16*8 = 1024 blocks
    kn_sgemm<<<(T / 128) * (L / 128) * B, 512, 0, stream>>>
        (Qbf, Kbf, S, rowsum, L, Dp, T, (long)T * Dp, (long)L * Dp, (long)T * L, 0.0625f, 4);

    // Z[b] = (Sexp @ HT^T)/rowsum: [1024 x 1024], 128^2 tiles -> 8*8*8 = 512 blocks
    kn_pv<<<(T / 128) * (Dh / 128) * B, 512, 0, stream>>>
        (S, HT, Z, rowsum, Dh, L, T, (long)T * L, (long)Dh * L, (long)T * Dh, 3);
}

// Round 12
// 149.489 us; speedup vs baseline: 1.0287x; 1.0287x over previous
//
#include <hip/hip_runtime.h>
#include <hip/hip_bf16.h>
#include <type_traits>

// Dims: B=8, L=2048, T=1024, Dh=1024, Dg=768, Dp=256
// Pipeline: HT=transpose(H); Q=G@Wq^T; K=H@Wk^T; Sexp=exp(Q@K^T/16)[+rowsum];
//           Z=(Sexp@HT^T)/rowsum
// R12: PV = R10's measured-best (256x128, 3-buf, reg-dbuf frags).
//      S-GEMM = full-K-resident (K=256 entirely in LDS, 16 loads/thread upfront,
//      4 phases of vmcnt(12/8/4/0)+barrier+MFMA; no restaging).
// Workspace (u16): Qbf 2M | Kbf 4M | HT 16M | S 16M | rowsum f32 B*T

typedef float    f32x4  __attribute__((ext_vector_type(4)));
typedef __bf16   bf16x8 __attribute__((ext_vector_type(8)));
typedef unsigned short u16x8 __attribute__((ext_vector_type(8)));

__device__ __forceinline__ unsigned short f2bf(float f) {
    union { float f; unsigned u; } x; x.f = f;
    return (unsigned short)((x.u + 0x7fffu + ((x.u >> 16) & 1u)) >> 16);
}
__device__ __forceinline__ float bf2f(unsigned short u) {
    union { unsigned u; float f; } x; x.u = ((unsigned)u) << 16;
    return x.f;
}
__device__ __forceinline__ void gload_lds16(const unsigned short* g, unsigned short* l) {
    __builtin_amdgcn_global_load_lds(
        (const __attribute__((address_space(1))) void*)g,
        (__attribute__((address_space(3))) void*)l, 16, 0, 0);
}

// ---------------- transpose: H [L,Dh] f32 -> HT [Dh,L] bf16; 64x64 tiles ----------------
__global__ __launch_bounds__(256) void kn_transp(const float* __restrict__ H,
                                                 unsigned short* __restrict__ HT,
                                                 int L, int D) {
    __shared__ float tile[64][65];
    int b = blockIdx.z;
    const float* src = H + (size_t)b * L * D;
    unsigned short* dstT = HT + (size_t)b * L * D;
    int l0 = blockIdx.y * 64, d0 = blockIdx.x * 64;
    int tx = threadIdx.x, ty = threadIdx.y;
#pragma unroll
    for (int i = ty; i < 64; i += 4)
        tile[i][tx] = src[(size_t)(l0 + i) * D + d0 + tx];
    __syncthreads();
#pragma unroll
    for (int i = ty; i < 64; i += 4)
        dstT[(size_t)(d0 + i) * L + l0 + tx] = f2bf(tile[tx][i]);
}

// -------- projection: C[M,N]=A[M,K]@B^T[N,K], f32 in, bf16 out; TM x 128 tile --------
template<int TM, int WM>
__device__ __forceinline__ void proj_body(const float* __restrict__ A,
                                          const float* __restrict__ B,
                                          unsigned short* __restrict__ C,
                                          int N, int K, int gxs) {
    constexpr int WN  = 4 / WM;
    constexpr int MF  = (TM / WM) / 16;
    constexpr int NF  = (128 / WN) / 16;
    constexpr int CHA = TM * 8;
    constexpr int CHT = CHA + 1024;
    constexpr int CPT = CHT / 256;
    constexpr int BUFU = TM * 64 + 128 * 64;
    constexpr int LDSB = (2 * BUFU * 2 > TM * 132 * 4) ? 2 * BUFU * 2 : TM * 132 * 4;
    __shared__ __align__(16) char smem_raw[LDSB];
    unsigned short* base = (unsigned short*)smem_raw;
    float* st = (float*)smem_raw;

    int tid = threadIdx.x;
    int t = blockIdx.x;
    int by = t >> gxs;
    int bx = t & ((1 << gxs) - 1);
    const float* Ab = A + (size_t)by * TM * K;
    const float* Bb = B + (size_t)bx * 128 * K;

    int lane = tid & 63;
    int wid = tid >> 6;
    int wr = wid / WN, wc = wid % WN;
    int lr = lane & 15;
    int lg = lane >> 4;
    int xoff = (lane & 7) << 3;

    f32x4 rv[CPT][2];
    f32x4 acc[MF][NF] = {};

    auto LOAD = [&](int k0) {
#pragma unroll
        for (int c = 0; c < CPT; ++c) {
            int ch = c * 256 + tid;
            const float* src;
            if (ch < CHA) {
                int row = ch >> 3;
                src = Ab + (size_t)row * K + k0 + (ch & 7) * 8;
            } else {
                int bc = ch - CHA;
                int row = bc >> 3;
                src = Bb + (size_t)row * K + k0 + (bc & 7) * 8;
            }
            rv[c][0] = *(const f32x4*)src;
            rv[c][1] = *(const f32x4*)(src + 4);
        }
    };
    auto WRITE = [&](int buf) {
        unsigned short* dA = base + buf * BUFU;
        unsigned short* dB = dA + TM * 64;
#pragma unroll
        for (int c = 0; c < CPT; ++c) {
            int ch = c * 256 + tid;
            u16x8 o;
#pragma unroll
            for (int j = 0; j < 4; ++j) { o[j] = f2bf(rv[c][0][j]); o[4 + j] = f2bf(rv[c][1][j]); }
            if (ch < CHA) {
                int row = ch >> 3;
                int sl = (ch & 7) ^ (row & 7);
                *(u16x8*)&dA[row * 64 + sl * 8] = o;
            } else {
                int bc = ch - CHA;
                int row = bc >> 3;
                int sl = (bc & 7) ^ (row & 7);
                *(u16x8*)&dB[row * 64 + sl * 8] = o;
            }
        }
    };
    auto COMPUTE = [&](int buf) {
        unsigned short* pA = base + buf * BUFU;
        unsigned short* pB = pA + TM * 64;
#pragma unroll
        for (int kk = 0; kk < 2; ++kk) {
            int kb = (kk * 32 + lg * 8) ^ xoff;
            bf16x8 af[MF], bfr[NF];
#pragma unroll
            for (int m = 0; m < MF; ++m)
                af[m] = *(const bf16x8*)&pA[(wr * MF * 16 + m * 16 + lr) * 64 + kb];
#pragma unroll
            for (int n = 0; n < NF; ++n)
                bfr[n] = *(const bf16x8*)&pB[(wc * NF * 16 + n * 16 + lr) * 64 + kb];
#pragma unroll
            for (int m = 0; m < MF; ++m)
#pragma unroll
                for (int n = 0; n < NF; ++n)
                    acc[m][n] = __builtin_amdgcn_mfma_f32_16x16x32_bf16(af[m], bfr[n], acc[m][n], 0, 0, 0);
        }
    };

    int nt = K / 64;
    LOAD(0);
    WRITE(0);
    __syncthreads();
    int buf = 0;
    for (int tt = 0; tt < nt; ++tt) {
        if (tt + 1 < nt) LOAD((tt + 1) * 64);
        COMPUTE(buf);
        if (tt + 1 < nt) WRITE(buf ^ 1);
        __syncthreads();
        buf ^= 1;
    }

#pragma unroll
    for (int m = 0; m < MF; ++m) {
        int r0 = wr * MF * 16 + m * 16 + lg * 4;
#pragma unroll
        for (int n = 0; n < NF; ++n) {
            int c0 = wc * NF * 16 + n * 16 + lr;
#pragma unroll
            for (int j = 0; j < 4; ++j)
                st[(r0 + j) * 132 + c0] = acc[m][n][j];
        }
    }
    __syncthreads();
    constexpr int TPR = 256 / TM;
    constexpr int CW  = 128 / TPR;
    int r  = tid / TPR;
    int c0 = (tid % TPR) * CW;
    size_t grow = (size_t)(by * TM + r) * N + bx * 128 + c0;
#pragma unroll
    for (int g = 0; g < CW / 8; ++g) {
        f32x4 a = *(const f32x4*)&st[r * 132 + c0 + g * 8];
        f32x4 b = *(const f32x4*)&st[r * 132 + c0 + g * 8 + 4];
        u16x8 o;
#pragma unroll
        for (int j = 0; j < 4; ++j) { o[j] = f2bf(a[j]); o[4 + j] = f2bf(b[j]); }
        *(u16x8*)&C[grow + g * 8] = o;
    }
}

__global__ __launch_bounds__(256) void kn_qproj(const float* A, const float* B,
                                                unsigned short* C, int N, int K, int gxs) {
    proj_body<32, 1>(A, B, C, N, K, gxs);
}
__global__ __launch_bounds__(256) void kn_kproj(const float* A, const float* B,
                                                unsigned short* C, int N, int K, int gxs) {
    proj_body<64, 2>(A, B, C, N, K, gxs);
}

// ------- S-GEMM: 128x128 tile, K=256 fully LDS-resident. 512 thr = 8 waves (4Mx2N).
//         All 16 loads/thread issued upfront (phase-major order); 4 phases of
//         {vmcnt(12/8/4/0) -> barrier -> 8 MFMA}. Fused exp + rowsum atomics. -------
__global__ __launch_bounds__(512) void kn_sgemm(const unsigned short* __restrict__ A,
                                                const unsigned short* __restrict__ B,
                                                unsigned short* __restrict__ C,
                                                float* __restrict__ rowsum,
                                                int N, int Trows,
                                                long batchA, long batchB, long batchC,
                                                float scale, int gxs) {
    constexpr int K = 256;
    __shared__ __align__(16) unsigned short sm[128 * 256 * 2];   // A 64KB | B 64KB
    unsigned short* sA = sm;
    unsigned short* sB = sm + 128 * 256;
    float* st = (float*)sm;                                       // epilogue overlay

    int tid = threadIdx.x;
    int wg = blockIdx.x;
    int bz = wg & 7;
    int t = wg >> 3;
    int by = t >> gxs;
    int bx = t & ((1 << gxs) - 1);

    const unsigned short* Ab = A + (size_t)bz * batchA + (size_t)by * 128 * K;
    const unsigned short* Bb = B + (size_t)bz * batchB + (size_t)bx * 128 * K;
    unsigned short* Cb = C + (size_t)bz * batchC;
    float* rs = rowsum + (size_t)bz * Trows;

    int lane = tid & 63;
    int wid = tid >> 6;
    int wr = wid >> 1, wc = wid & 1;      // 4M x 2N; wave-tile 32x64
    int lr = lane & 15;
    int lg = lane >> 4;
    int xoff = (lane & 7) << 3;

    // issue ALL staging, phase-major: per phase p (64 K-elems): 1024 A-chunks + 1024 B.
    // LDS layout per phase: region p*16KB within sA/sB; row stride 64 u16; swizzled.
#pragma unroll
    for (int p = 0; p < 4; ++p) {
#pragma unroll
        for (int c = 0; c < 2; ++c) {
            int ch = c * 512 + tid;           // 0..1023 within phase
            int row = ch >> 3;
            int g8 = (ch & 7) ^ (row & 7);
            gload_lds16(Ab + (size_t)row * K + p * 64 + g8 * 8, sA + p * 8192 + ch * 8);
        }
#pragma unroll
        for (int c = 0; c < 2; ++c) {
            int ch = c * 512 + tid;
            int row = ch >> 3;
            int g8 = (ch & 7) ^ (row & 7);
            gload_lds16(Bb + (size_t)row * K + p * 64 + g8 * 8, sB + p * 8192 + ch * 8);
        }
    }

    f32x4 acc[2][4] = {};
#pragma unroll
    for (int p = 0; p < 4; ++p) {
        if (p == 0)      asm volatile("s_waitcnt vmcnt(12)" ::: "memory");
        else if (p == 1) asm volatile("s_waitcnt vmcnt(8)" ::: "memory");
        else if (p == 2) asm volatile("s_waitcnt vmcnt(4)" ::: "memory");
        else             asm volatile("s_waitcnt vmcnt(0)" ::: "memory");
        __builtin_amdgcn_s_barrier();
        unsigned short* pA = sA + p * 8192;
        unsigned short* pB = sB + p * 8192;
#pragma unroll
        for (int kk = 0; kk < 2; ++kk) {
            int kb = (kk * 32 + lg * 8) ^ xoff;
            bf16x8 af[2], bfr[4];
#pragma unroll
            for (int m = 0; m < 2; ++m)
                af[m] = *(const bf16x8*)&pA[(wr * 32 + m * 16 + lr) * 64 + kb];
#pragma unroll
            for (int n = 0; n < 4; ++n)
                bfr[n] = *(const bf16x8*)&pB[(wc * 64 + n * 16 + lr) * 64 + kb];
#pragma unroll
            for (int m = 0; m < 2; ++m)
#pragma unroll
                for (int n = 0; n < 4; ++n)
                    acc[m][n] = __builtin_amdgcn_mfma_f32_16x16x32_bf16(af[m], bfr[n], acc[m][n], 0, 0, 0);
        }
    }
    __syncthreads();    // all LDS frag reads done before st overlay

    // epilogue: 4 quarters (32 rows each) via st; exp + bf16 store + rowsum atomics
#pragma unroll
    for (int q = 0; q < 4; ++q) {
        if (wr == q) {
#pragma unroll
            for (int m = 0; m < 2; ++m) {
                int rl = m * 16 + lg * 4;             // 0..31
#pragma unroll
                for (int n = 0; n < 4; ++n) {
                    int col = wc * 64 + n * 16 + lr;
#pragma unroll
                    for (int j = 0; j < 4; ++j)
                        st[(rl + j) * 132 + col] = acc[m][n][j] * scale;
                }
            }
        }
        __syncthreads();
        int r  = tid >> 4;                 // 0..31
        int c0 = (tid & 15) * 8;
        int grow_r = by * 128 + q * 32 + r;
        size_t grow = (size_t)grow_r * N + bx * 128 + c0;
        f32x4 a = *(const f32x4*)&st[r * 132 + c0];
        f32x4 b = *(const f32x4*)&st[r * 132 + c0 + 4];
        u16x8 o;
        float psum = 0.f;
#pragma unroll
        for (int j = 0; j < 4; ++j) {
            o[j]     = f2bf(__expf(a[j]));
            o[4 + j] = f2bf(__expf(b[j]));
            psum += bf2f(o[j]) + bf2f(o[4 + j]);
        }
        *(u16x8*)&Cb[grow] = o;
        psum += __shfl_xor(psum, 1);
        psum += __shfl_xor(psum, 2);
        psum += __shfl_xor(psum, 4);
        psum += __shfl_xor(psum, 8);
        if ((tid & 15) == 0)
            atomicAdd(&rs[grow_r], psum);
        __syncthreads();
    }
}

// ------- PV (R10 best): 256x128, BK=64, 8 waves, 3-buf LDS, register-dbuf frags.
//         Epilogue divides by rowsum. -------
__global__ __launch_bounds__(512) void kn_pv(const unsigned short* __restrict__ A,
                                             const unsigned short* __restrict__ B,
                                             float* __restrict__ C,
                                             const float* __restrict__ rowsum,
                                             int N, int K, int Trows,
                                             long batchA, long batchB, long batchC,
                                             int gxs) {
    __shared__ __align__(16) char smem_raw[3 * 49152];       // 144KB
    unsigned short* base = (unsigned short*)smem_raw;
    float* st = (float*)smem_raw;

    int tid = threadIdx.x;
    int wg = blockIdx.x;
    int bz = wg & 7;
    int t = wg >> 3;
    int by = t >> gxs;
    int bx = t & ((1 << gxs) - 1);

    const unsigned short* Ab = A + (size_t)bz * batchA + (size_t)by * 256 * K;
    const unsigned short* Bb = B + (size_t)bz * batchB + (size_t)bx * 128 * K;
    float* Cb = C + (size_t)bz * batchC;
    const float* rs = rowsum + (size_t)bz * Trows;

    int lane = tid & 63;
    int wid = tid >> 6;
    int wr = wid >> 1, wc = wid & 1;
    int lr = lane & 15;
    int lg = lane >> 4;
    int xoff = (lane & 7) << 3;

    f32x4 acc[4][4] = {};
    bf16x8 fA0[4], fB0[4], fA1[4], fB1[4];

    auto STAGE_HALF = [&](int buf, int k0, int half) {
        unsigned short* dA = base + buf * 24576;
        unsigned short* dB = dA + 16384;
#pragma unroll
        for (int c = 0; c < 3; ++c) {
            int ch = half * 1536 + c * 512 + tid;
            if (ch < 2048) {
                int row = ch >> 3;
                int g8 = (ch & 7) ^ (row & 7);
                gload_lds16(Ab + (size_t)row * K + k0 + g8 * 8, dA + ch * 8);
            } else {
                int bc = ch - 2048;
                int row = bc >> 3;
                int g8 = (bc & 7) ^ (row & 7);
                gload_lds16(Bb + (size_t)row * K + k0 + g8 * 8, dB + bc * 8);
            }
        }
    };
    auto LDFRAG = [&](int buf, int kk, bf16x8* fa, bf16x8* fb) {
        unsigned short* pA = base + buf * 24576;
        unsigned short* pB = pA + 16384;
        int kb = (kk * 32 + lg * 8) ^ xoff;
#pragma unroll
        for (int m = 0; m < 4; ++m)
            fa[m] = *(const bf16x8*)&pA[(wr * 64 + m * 16 + lr) * 64 + kb];
#pragma unroll
        for (int n = 0; n < 4; ++n)
            fb[n] = *(const bf16x8*)&pB[(wc * 64 + n * 16 + lr) * 64 + kb];
    };

    int nt = K / 64;                           // 32
    STAGE_HALF(0, 0, 0);   STAGE_HALF(0, 0, 1);
    STAGE_HALF(1, 64, 0);  STAGE_HALF(1, 64, 1);
    asm volatile("s_waitcnt vmcnt(6)" ::: "memory");
    __builtin_amdgcn_s_barrier();
    LDFRAG(0, 0, fA0, fB0);

    int cur = 0;
    for (int tt = 0; tt < nt; ++tt) {
        int nb  = (cur >= 1) ? cur - 1 : 2;
        int nxt = (cur == 2) ? 0 : cur + 1;
        if (tt + 2 < nt) STAGE_HALF(nb, (tt + 2) * 64, 0);
        LDFRAG(cur, 1, fA1, fB1);
        __builtin_amdgcn_sched_barrier(0);
        __builtin_amdgcn_s_setprio(1);
#pragma unroll
        for (int m = 0; m < 4; ++m)
#pragma unroll
            for (int n = 0; n < 4; ++n)
                acc[m][n] = __builtin_amdgcn_mfma_f32_16x16x32_bf16(fA0[m], fB0[n], acc[m][n], 0, 0, 0);
        __builtin_amdgcn_s_setprio(0);
        __builtin_amdgcn_sched_barrier(0);
        if (tt + 2 < nt) STAGE_HALF(nb, (tt + 2) * 64, 1);
        __builtin_amdgcn_sched_barrier(0);
        __builtin_amdgcn_s_setprio(1);
#pragma unroll
        for (int m = 0; m < 4; ++m)
#pragma unroll
            for (int n = 0; n < 4; ++n)
                acc[m][n] = __builtin_amdgcn_mfma_f32_16x16x32_bf16(fA1[m], fB1[n], acc[m][n], 0, 0, 0);
        __builtin_amdgcn_s_setprio(0);
        __builtin_amdgcn_sched_barrier(0);
        if (tt + 1 < nt) {
            if (tt + 2 < nt) asm volatile("s_waitcnt vmcnt(6)" ::: "memory");
            else             asm volatile("s_waitcnt vmcnt(0)" ::: "memory");
            LDFRAG(nxt, 0, fA0, fB0);
            __builtin_amdgcn_sched_barrier(0);
            __builtin_amdgcn_s_barrier();
        }
        cur = nxt;
    }
    __syncthreads();

#pragma unroll
    for (int q = 0; q < 4; ++q) {
        if (wr == q) {
#pragma unroll
            for (int m = 0; m < 4; ++m) {
                int rl = m * 16 + lg * 4;
#pragma unroll
                for (int n = 0; n < 4; ++n) {
                    int col = wc * 64 + n * 16 + lr;
#pragma unroll
                    for (int j = 0; j < 4; ++j)
                        st[(rl + j) * 132 + col] = acc[m][n][j];
                }
            }
        }
        __syncthreads();
        int r = tid >> 3;
        int c0 = (tid & 7) * 16;
        float inv = 1.0f / rs[by * 256 + q * 64 + r];
        size_t grow = (size_t)(by * 256 + q * 64 + r) * N + bx * 128 + c0;
#pragma unroll
        for (int g = 0; g < 4; ++g) {
            f32x4 v = *(const f32x4*)&st[r * 132 + c0 + g * 4];
#pragma unroll
            for (int j = 0; j < 4; ++j) v[j] *= inv;
            *(f32x4*)&Cb[grow + g * 4] = v;
        }
        __syncthreads();
    }
}

extern "C" void kernel_launch(void* const* d_in, const int* in_sizes, int n_in,
                              void* d_out, int out_size, void* d_ws, size_t ws_size,
                              hipStream_t stream) {
    constexpr int B = 8, L = 2048, T = 1024, Dh = 1024, Dg = 768, Dp = 256;
    const float* H  = (const float*)d_in[0];
    const float* G  = (const float*)d_in[1];
    const float* Wq = (const float*)d_in[2];
    const float* Wk = (const float*)d_in[3];
    float* Z = (float*)d_out;

    unsigned short* Qbf = (unsigned short*)d_ws;             // B*T*Dp  = 2M
    unsigned short* Kbf = Qbf + (size_t)B * T * Dp;          // B*L*Dp  = 4M
    unsigned short* HT  = Kbf + (size_t)B * L * Dp;          // B*Dh*L  = 16M
    unsigned short* S   = HT  + (size_t)B * Dh * L;          // B*T*L   = 16M
    float* rowsum = (float*)(S + (size_t)B * T * L);         // B*T f32

    hipMemsetAsync(rowsum, 0, (size_t)B * T * sizeof(float), stream);

    kn_transp<<<dim3(Dh / 64, L / 64, B), dim3(64, 4), 0, stream>>>(H, HT, L, Dh);

    kn_qproj<<<(B * T / 32) * (Dp / 128), 256, 0, stream>>>(G, Wq, Qbf, Dp, Dg, 1);

    kn_kproj<<<(B * L / 64) * (Dp / 128), 256, 0, stream>>>(H, Wk, Kbf, Dp, Dh, 1);

    // Sexp = exp(Q@K^T/16): 128^2 tiles, K-resident; grid 8*16*8 = 1024
    kn_sgemm<<<(T / 128) * (L / 128) * B, 512, 0, stream>>>
        (Qbf, Kbf, S, rowsum, L, T, (long)T * Dp, (long)L * Dp, (long)T * L, 0.0625f, 4);

    // Z = (Sexp @ HT^T)/rowsum: 256x128 tiles; grid 4*8*8 = 256
    kn_pv<<<(T / 256) * (Dh / 128) * B, 512, 0, stream>>>
        (S, HT, Z, rowsum, Dh, L, T, (long)T * L, (long)Dh * L, (long)T * Dh, 3);
}

// Round 13
// 148.246 us; speedup vs baseline: 1.0373x; 1.0084x over previous
//
#include <hip/hip_runtime.h>
#include <hip/hip_bf16.h>
#include <type_traits>

// Dims: B=8, L=2048, T=1024, Dh=1024, Dg=768, Dp=256
// Pipeline: HT=transpose(H); Q=G@Wq^T; K=H@Wk^T; Sexp=exp(Q@K^T/16)[+rowsum];
//           Z=(Sexp@HT^T)/rowsum
// R13: PV -> BK=32, 6-buffer, depth-5 counted-vmcnt pipeline, 1 barrier/iter.
//      sgemm reverted to R10's 256x128 sbuf. f2bf -> native __bf16 cvt.
// Workspace (u16): Qbf 2M | Kbf 4M | HT 16M | S 16M | rowsum f32 B*T

typedef float    f32x4  __attribute__((ext_vector_type(4)));
typedef __bf16   bf16x8 __attribute__((ext_vector_type(8)));
typedef unsigned short u16x8 __attribute__((ext_vector_type(8)));

__device__ __forceinline__ unsigned short f2bf(float f) {
    union { __bf16 b; unsigned short u; } c;
    c.b = (__bf16)f;                       // native RNE cvt (v_cvt_pk_bf16_f32)
    return c.u;
}
__device__ __forceinline__ float bf2f(unsigned short u) {
    union { unsigned u; float f; } x; x.u = ((unsigned)u) << 16;
    return x.f;
}
__device__ __forceinline__ void gload_lds16(const unsigned short* g, unsigned short* l) {
    __builtin_amdgcn_global_load_lds(
        (const __attribute__((address_space(1))) void*)g,
        (__attribute__((address_space(3))) void*)l, 16, 0, 0);
}

// ---------------- transpose: H [L,Dh] f32 -> HT [Dh,L] bf16; 64x64 tiles ----------------
__global__ __launch_bounds__(256) void kn_transp(const float* __restrict__ H,
                                                 unsigned short* __restrict__ HT,
                                                 int L, int D) {
    __shared__ float tile[64][65];
    int b = blockIdx.z;
    const float* src = H + (size_t)b * L * D;
    unsigned short* dstT = HT + (size_t)b * L * D;
    int l0 = blockIdx.y * 64, d0 = blockIdx.x * 64;
    int tx = threadIdx.x, ty = threadIdx.y;
#pragma unroll
    for (int i = ty; i < 64; i += 4)
        tile[i][tx] = src[(size_t)(l0 + i) * D + d0 + tx];
    __syncthreads();
#pragma unroll
    for (int i = ty; i < 64; i += 4)
        dstT[(size_t)(d0 + i) * L + l0 + tx] = f2bf(tile[tx][i]);
}

// -------- projection: C[M,N]=A[M,K]@B^T[N,K], f32 in, bf16 out; TM x 128 tile --------
template<int TM, int WM>
__device__ __forceinline__ void proj_body(const float* __restrict__ A,
                                          const float* __restrict__ B,
                                          unsigned short* __restrict__ C,
                                          int N, int K, int gxs) {
    constexpr int WN  = 4 / WM;
    constexpr int MF  = (TM / WM) / 16;
    constexpr int NF  = (128 / WN) / 16;
    constexpr int CHA = TM * 8;
    constexpr int CHT = CHA + 1024;
    constexpr int CPT = CHT / 256;
    constexpr int BUFU = TM * 64 + 128 * 64;
    constexpr int LDSB = (2 * BUFU * 2 > TM * 132 * 4) ? 2 * BUFU * 2 : TM * 132 * 4;
    __shared__ __align__(16) char smem_raw[LDSB];
    unsigned short* base = (unsigned short*)smem_raw;
    float* st = (float*)smem_raw;

    int tid = threadIdx.x;
    int t = blockIdx.x;
    int by = t >> gxs;
    int bx = t & ((1 << gxs) - 1);
    const float* Ab = A + (size_t)by * TM * K;
    const float* Bb = B + (size_t)bx * 128 * K;

    int lane = tid & 63;
    int wid = tid >> 6;
    int wr = wid / WN, wc = wid % WN;
    int lr = lane & 15;
    int lg = lane >> 4;
    int xoff = (lane & 7) << 3;

    f32x4 rv[CPT][2];
    f32x4 acc[MF][NF] = {};

    auto LOAD = [&](int k0) {
#pragma unroll
        for (int c = 0; c < CPT; ++c) {
            int ch = c * 256 + tid;
            const float* src;
            if (ch < CHA) {
                int row = ch >> 3;
                src = Ab + (size_t)row * K + k0 + (ch & 7) * 8;
            } else {
                int bc = ch - CHA;
                int row = bc >> 3;
                src = Bb + (size_t)row * K + k0 + (bc & 7) * 8;
            }
            rv[c][0] = *(const f32x4*)src;
            rv[c][1] = *(const f32x4*)(src + 4);
        }
    };
    auto WRITE = [&](int buf) {
        unsigned short* dA = base + buf * BUFU;
        unsigned short* dB = dA + TM * 64;
#pragma unroll
        for (int c = 0; c < CPT; ++c) {
            int ch = c * 256 + tid;
            u16x8 o;
#pragma unroll
            for (int j = 0; j < 4; ++j) { o[j] = f2bf(rv[c][0][j]); o[4 + j] = f2bf(rv[c][1][j]); }
            if (ch < CHA) {
                int row = ch >> 3;
                int sl = (ch & 7) ^ (row & 7);
                *(u16x8*)&dA[row * 64 + sl * 8] = o;
            } else {
                int bc = ch - CHA;
                int row = bc >> 3;
                int sl = (bc & 7) ^ (row & 7);
                *(u16x8*)&dB[row * 64 + sl * 8] = o;
            }
        }
    };
    auto COMPUTE = [&](int buf) {
        unsigned short* pA = base + buf * BUFU;
        unsigned short* pB = pA + TM * 64;
#pragma unroll
        for (int kk = 0; kk < 2; ++kk) {
            int kb = (kk * 32 + lg * 8) ^ xoff;
            bf16x8 af[MF], bfr[NF];
#pragma unroll
            for (int m = 0; m < MF; ++m)
                af[m] = *(const bf16x8*)&pA[(wr * MF * 16 + m * 16 + lr) * 64 + kb];
#pragma unroll
            for (int n = 0; n < NF; ++n)
                bfr[n] = *(const bf16x8*)&pB[(wc * NF * 16 + n * 16 + lr) * 64 + kb];
#pragma unroll
            for (int m = 0; m < MF; ++m)
#pragma unroll
                for (int n = 0; n < NF; ++n)
                    acc[m][n] = __builtin_amdgcn_mfma_f32_16x16x32_bf16(af[m], bfr[n], acc[m][n], 0, 0, 0);
        }
    };

    int nt = K / 64;
    LOAD(0);
    WRITE(0);
    __syncthreads();
    int buf = 0;
    for (int tt = 0; tt < nt; ++tt) {
        if (tt + 1 < nt) LOAD((tt + 1) * 64);
        COMPUTE(buf);
        if (tt + 1 < nt) WRITE(buf ^ 1);
        __syncthreads();
        buf ^= 1;
    }

#pragma unroll
    for (int m = 0; m < MF; ++m) {
        int r0 = wr * MF * 16 + m * 16 + lg * 4;
#pragma unroll
        for (int n = 0; n < NF; ++n) {
            int c0 = wc * NF * 16 + n * 16 + lr;
#pragma unroll
            for (int j = 0; j < 4; ++j)
                st[(r0 + j) * 132 + c0] = acc[m][n][j];
        }
    }
    __syncthreads();
    constexpr int TPR = 256 / TM;
    constexpr int CW  = 128 / TPR;
    int r  = tid / TPR;
    int c0 = (tid % TPR) * CW;
    size_t grow = (size_t)(by * TM + r) * N + bx * 128 + c0;
#pragma unroll
    for (int g = 0; g < CW / 8; ++g) {
        f32x4 a = *(const f32x4*)&st[r * 132 + c0 + g * 8];
        f32x4 b = *(const f32x4*)&st[r * 132 + c0 + g * 8 + 4];
        u16x8 o;
#pragma unroll
        for (int j = 0; j < 4; ++j) { o[j] = f2bf(a[j]); o[4 + j] = f2bf(b[j]); }
        *(u16x8*)&C[grow + g * 8] = o;
    }
}

__global__ __launch_bounds__(256) void kn_qproj(const float* A, const float* B,
                                                unsigned short* C, int N, int K, int gxs) {
    proj_body<32, 1>(A, B, C, N, K, gxs);
}
__global__ __launch_bounds__(256) void kn_kproj(const float* A, const float* B,
                                                unsigned short* C, int N, int K, int gxs) {
    proj_body<64, 2>(A, B, C, N, K, gxs);
}

// ------- S-GEMM (R10 best): 256x128, BK=64, 8 waves, single-buffer; epilogue stores
//         exp(s) bf16 and atomically accumulates f32 row sums. -------
__global__ __launch_bounds__(512) void kn_sgemm(const unsigned short* __restrict__ A,
                                                const unsigned short* __restrict__ B,
                                                unsigned short* __restrict__ C,
                                                float* __restrict__ rowsum,
                                                int N, int K, int Trows,
                                                long batchA, long batchB, long batchC,
                                                float scale, int gxs) {
    __shared__ __align__(16) char smem_raw[49152];
    unsigned short* base = (unsigned short*)smem_raw;
    float* st = (float*)smem_raw;

    int tid = threadIdx.x;
    int wg = blockIdx.x;
    int bz = wg & 7;
    int t = wg >> 3;
    int by = t >> gxs;
    int bx = t & ((1 << gxs) - 1);

    const unsigned short* Ab = A + (size_t)bz * batchA + (size_t)by * 256 * K;
    const unsigned short* Bb = B + (size_t)bz * batchB + (size_t)bx * 128 * K;
    unsigned short* Cb = C + (size_t)bz * batchC;
    float* rs = rowsum + (size_t)bz * Trows;

    int lane = tid & 63;
    int wid = tid >> 6;
    int wr = wid >> 1, wc = wid & 1;
    int lr = lane & 15;
    int lg = lane >> 4;
    int xoff = (lane & 7) << 3;

    f32x4 acc[4][4] = {};

    for (int k0 = 0; k0 < K; k0 += 64) {
#pragma unroll
        for (int c = 0; c < 6; ++c) {
            int ch = c * 512 + tid;
            if (ch < 2048) {
                int row = ch >> 3;
                int g8 = (ch & 7) ^ (row & 7);
                gload_lds16(Ab + (size_t)row * K + k0 + g8 * 8, base + ch * 8);
            } else {
                int bc = ch - 2048;
                int row = bc >> 3;
                int g8 = (bc & 7) ^ (row & 7);
                gload_lds16(Bb + (size_t)row * K + k0 + g8 * 8, base + 16384 + bc * 8);
            }
        }
        __syncthreads();
#pragma unroll
        for (int kk = 0; kk < 2; ++kk) {
            int kb = (kk * 32 + lg * 8) ^ xoff;
            bf16x8 af[4], bfr[4];
#pragma unroll
            for (int m = 0; m < 4; ++m)
                af[m] = *(const bf16x8*)&base[(wr * 64 + m * 16 + lr) * 64 + kb];
#pragma unroll
            for (int n = 0; n < 4; ++n)
                bfr[n] = *(const bf16x8*)&base[16384 + (wc * 64 + n * 16 + lr) * 64 + kb];
#pragma unroll
            for (int m = 0; m < 4; ++m)
#pragma unroll
                for (int n = 0; n < 4; ++n)
                    acc[m][n] = __builtin_amdgcn_mfma_f32_16x16x32_bf16(af[m], bfr[n], acc[m][n], 0, 0, 0);
        }
        __syncthreads();
    }

#pragma unroll
    for (int q = 0; q < 4; ++q) {
        if (wr == q) {
#pragma unroll
            for (int m = 0; m < 4; ++m) {
                int rl = m * 16 + lg * 4;
#pragma unroll
                for (int n = 0; n < 4; ++n) {
                    int col = wc * 64 + n * 16 + lr;
#pragma unroll
                    for (int j = 0; j < 4; ++j)
                        st[(rl + j) * 132 + col] = acc[m][n][j] * scale;
                }
            }
        }
        __syncthreads();
        int r = tid >> 3;
        int c0 = (tid & 7) * 16;
        int grow_r = by * 256 + q * 64 + r;
        size_t grow = (size_t)grow_r * N + bx * 128 + c0;
        float psum = 0.f;
#pragma unroll
        for (int g = 0; g < 2; ++g) {
            f32x4 a = *(const f32x4*)&st[r * 132 + c0 + g * 8];
            f32x4 b = *(const f32x4*)&st[r * 132 + c0 + g * 8 + 4];
            u16x8 o;
#pragma unroll
            for (int j = 0; j < 4; ++j) {
                o[j]     = f2bf(__expf(a[j]));
                o[4 + j] = f2bf(__expf(b[j]));
                psum += bf2f(o[j]) + bf2f(o[4 + j]);
            }
            *(u16x8*)&Cb[grow + g * 8] = o;
        }
        psum += __shfl_xor(psum, 1);
        psum += __shfl_xor(psum, 2);
        psum += __shfl_xor(psum, 4);
        if ((tid & 7) == 0)
            atomicAdd(&rs[grow_r], psum);
        __syncthreads();
    }
}

// ------- PV: 256x128 tile, BK=32, 6-buf LDS (144KB), depth-5 counted-vmcnt pipeline,
//         1 raw barrier/iter. Epilogue divides by rowsum. -------
__global__ __launch_bounds__(512) void kn_pv(const unsigned short* __restrict__ A,
                                             const unsigned short* __restrict__ B,
                                             float* __restrict__ C,
                                             const float* __restrict__ rowsum,
                                             int N, int K, int Trows,
                                             long batchA, long batchB, long batchC,
                                             int gxs) {
    constexpr int BUFU = 256 * 32 + 128 * 32;              // 12288 u16 = 24KB/buf
    __shared__ __align__(16) unsigned short smem[6 * BUFU]; // 144KB
    float* st = (float*)smem;

    int tid = threadIdx.x;
    int wg = blockIdx.x;
    int bz = wg & 7;
    int t = wg >> 3;
    int by = t >> gxs;
    int bx = t & ((1 << gxs) - 1);

    const unsigned short* Ab = A + (size_t)bz * batchA + (size_t)by * 256 * K;
    const unsigned short* Bb = B + (size_t)bz * batchB + (size_t)bx * 128 * K;
    float* Cb = C + (size_t)bz * batchC;
    const float* rs = rowsum + (size_t)bz * Trows;

    int lane = tid & 63;
    int wid = tid >> 6;
    int wr = wid >> 1, wc = wid & 1;      // 4M x 2N; wave-tile 64x64
    int lr = lane & 15;
    int lg = lane >> 4;

    f32x4 acc[4][4] = {};

    // A-tile 256x32 bf16 = 1024 16B-chunks (4/row); B-tile 128x32 = 512 chunks.
    // LDS slot s of row r holds global slot s^(r&3)  (involution; read mirrors it).
    auto STAGE = [&](int buf, int k0) {
        unsigned short* dA = smem + buf * BUFU;
        unsigned short* dB = dA + 8192;
#pragma unroll
        for (int c = 0; c < 3; ++c) {
            int ch = c * 512 + tid;                        // 0..1535
            if (ch < 1024) {
                int row = ch >> 2;
                int g4 = (ch & 3) ^ (row & 3);
                gload_lds16(Ab + (size_t)row * K + k0 + g4 * 8, dA + ch * 8);
            } else {
                int bc = ch - 1024;
                int row = bc >> 2;
                int g4 = (bc & 3) ^ (row & 3);
                gload_lds16(Bb + (size_t)row * K + k0 + g4 * 8, dB + bc * 8);
            }
        }
    };

    int nt = K / 32;                                       // 64
    STAGE(0, 0); STAGE(1, 32); STAGE(2, 64); STAGE(3, 96); STAGE(4, 128);

    int ka = (lg ^ (lr & 3)) * 8;                          // swizzled k-slot (row&3 == lr&3)

    for (int tt = 0; tt < nt; ++tt) {
        int rem = nt - 1 - tt;
        if (rem >= 5)      asm volatile("s_waitcnt vmcnt(15)" ::: "memory");
        else if (rem == 4) asm volatile("s_waitcnt vmcnt(12)" ::: "memory");
        else if (rem == 3) asm volatile("s_waitcnt vmcnt(9)" ::: "memory");
        else if (rem == 2) asm volatile("s_waitcnt vmcnt(6)" ::: "memory");
        else if (rem == 1) asm volatile("s_waitcnt vmcnt(3)" ::: "memory");
        else               asm volatile("s_waitcnt vmcnt(0)" ::: "memory");
        __builtin_amdgcn_s_barrier();      // tile tt ready everywhere; prior reads done

        unsigned short* pA = smem + (tt % 6) * BUFU;
        unsigned short* pB = pA + 8192;
        bf16x8 fa[4], fb[4];
#pragma unroll
        for (int m = 0; m < 4; ++m)
            fa[m] = *(const bf16x8*)&pA[(wr * 64 + m * 16 + lr) * 32 + ka];
#pragma unroll
        for (int n = 0; n < 4; ++n)
            fb[n] = *(const bf16x8*)&pB[(wc * 64 + n * 16 + lr) * 32 + ka];

        if (tt + 5 < nt) STAGE((tt + 5) % 6, (tt + 5) * 32);   // refill buf (tt-1)%6
        __builtin_amdgcn_sched_barrier(0);

        __builtin_amdgcn_s_setprio(1);
#pragma unroll
        for (int m = 0; m < 4; ++m)
#pragma unroll
            for (int n = 0; n < 4; ++n)
                acc[m][n] = __builtin_amdgcn_mfma_f32_16x16x32_bf16(fa[m], fb[n], acc[m][n], 0, 0, 0);
        __builtin_amdgcn_s_setprio(0);
    }
    __syncthreads();                        // all LDS reads done before st overlay

    // epilogue: 4 quarters via st[64][132], divide by rowsum
#pragma unroll
    for (int q = 0; q < 4; ++q) {
        if (wr == q) {
#pragma unroll
            for (int m = 0; m < 4; ++m) {
                int rl = m * 16 + lg * 4;
#pragma unroll
                for (int n = 0; n < 4; ++n) {
                    int col = wc * 64 + n * 16 + lr;
#pragma unroll
                    for (int j = 0; j < 4; ++j)
                        st[(rl + j) * 132 + col] = acc[m][n][j];
                }
            }
        }
        __syncthreads();
        int r = tid >> 3;
        int c0 = (tid & 7) * 16;
        float inv = 1.0f / rs[by * 256 + q * 64 + r];
        size_t grow = (size_t)(by * 256 + q * 64 + r) * N + bx * 128 + c0;
#pragma unroll
        for (int g = 0; g < 4; ++g) {
            f32x4 v = *(const f32x4*)&st[r * 132 + c0 + g * 4];
#pragma unroll
            for (int j = 0; j < 4; ++j) v[j] *= inv;
            *(f32x4*)&Cb[grow + g * 4] = v;
        }
        __syncthreads();
    }
}

extern "C" void kernel_launch(void* const* d_in, const int* in_sizes, int n_in,
                              void* d_out, int out_size, void* d_ws, size_t ws_size,
                              hipStream_t stream) {
    constexpr int B = 8, L = 2048, T = 1024, Dh = 1024, Dg = 768, Dp = 256;
    const float* H  = (const float*)d_in[0];
    const float* G  = (const float*)d_in[1];
    const float* Wq = (const float*)d_in[2];
    const float* Wk = (const float*)d_in[3];
    float* Z = (float*)d_out;

    unsigned short* Qbf = (unsigned short*)d_ws;             // B*T*Dp  = 2M
    unsigned short* Kbf = Qbf + (size_t)B * T * Dp;          // B*L*Dp  = 4M
    unsigned short* HT  = Kbf + (size_t)B * L * Dp;          // B*Dh*L  = 16M
    unsigned short* S   = HT  + (size_t)B * Dh * L;          // B*T*L   = 16M
    float* rowsum = (float*)(S + (size_t)B * T * L);         // B*T f32

    hipMemsetAsync(rowsum, 0, (size_t)B * T * sizeof(float), stream);

    kn_transp<<<dim3(Dh / 64, L / 64, B), dim3(64, 4), 0, stream>>>(H, HT, L, Dh);

    kn_qproj<<<(B * T / 32) * (Dp / 128), 256, 0, stream>>>(G, Wq, Qbf, Dp, Dg, 1);

    kn_kproj<<<(B * L / 64) * (Dp / 128), 256, 0, stream>>>(H, Wk, Kbf, Dp, Dh, 1);

    // Sexp = exp(Q@K^T/16): 256x128 tiles; grid 2*16*8 = 256... (T/256)*(L/128)*B = 512
    kn_sgemm<<<(T / 256) * (L / 128) * B, 512, 0, stream>>>
        (Qbf, Kbf, S, rowsum, L, Dp, T, (long)T * Dp, (long)L * Dp, (long)T * L, 0.0625f, 4);

    // Z = (Sexp @ HT^T)/rowsum: 256x128 tiles, depth-5 pipeline; grid 4*8*8 = 256
    kn_pv<<<(T / 256) * (Dh / 128) * B, 512, 0, stream>>>
        (S, HT, Z, rowsum, Dh, L, T, (long)T * L, (long)Dh * L, (long)T * Dh, 3);
}

// Round 14
// 141.887 us; speedup vs baseline: 1.0838x; 1.0448x over previous
//
#include <hip/hip_runtime.h>
#include <hip/hip_bf16.h>
#include <type_traits>

// Dims: B=8, L=2048, T=1024, Dh=1024, Dg=768, Dp=256
// Pipeline: [HT,Hbf]=transpose+cast(H); Q=G@Wq^T; K=Hbf@Wk^T; Sexp=exp(Q@K^T/16)[+rowsum];
//           Z=(Sexp@HT^T)/rowsum
// R14: PV/sgemm = R10 measured-best. transp dual-writes Hbf. kproj = all-bf16 A via
//      global_load_lds (Wk reg-staged f32). Native v_cvt bf16 casts throughout.
// Workspace (u16): Qbf 2M | Kbf 4M | HT 16M | S 16M | Hbf 16M | rowsum f32  ~108MB

typedef float    f32x4  __attribute__((ext_vector_type(4)));
typedef __bf16   bf16x8 __attribute__((ext_vector_type(8)));
typedef unsigned short u16x8 __attribute__((ext_vector_type(8)));

__device__ __forceinline__ unsigned short f2bf(float f) {
    union { __bf16 b; unsigned short u; } c;
    c.b = (__bf16)f;                       // native RNE cvt
    return c.u;
}
__device__ __forceinline__ float bf2f(unsigned short u) {
    union { unsigned u; float f; } x; x.u = ((unsigned)u) << 16;
    return x.f;
}
__device__ __forceinline__ void gload_lds16(const unsigned short* g, unsigned short* l) {
    __builtin_amdgcn_global_load_lds(
        (const __attribute__((address_space(1))) void*)g,
        (__attribute__((address_space(3))) void*)l, 16, 0, 0);
}

// ------ transpose + dual cast: H [L,Dh] f32 -> HT [Dh,L] bf16 AND Hbf [L,Dh] bf16 ------
__global__ __launch_bounds__(256) void kn_transp(const float* __restrict__ H,
                                                 unsigned short* __restrict__ HT,
                                                 unsigned short* __restrict__ Hbf,
                                                 int L, int D) {
    __shared__ float tile[64][65];
    int b = blockIdx.z;
    const float* src = H + (size_t)b * L * D;
    unsigned short* dstT = HT + (size_t)b * L * D;
    unsigned short* dstN = Hbf + (size_t)b * L * D;
    int l0 = blockIdx.y * 64, d0 = blockIdx.x * 64;
    int tx = threadIdx.x, ty = threadIdx.y;
#pragma unroll
    for (int i = ty; i < 64; i += 4) {
        float v = src[(size_t)(l0 + i) * D + d0 + tx];
        tile[i][tx] = v;
        dstN[(size_t)(l0 + i) * D + d0 + tx] = f2bf(v);
    }
    __syncthreads();
#pragma unroll
    for (int i = ty; i < 64; i += 4)
        dstT[(size_t)(d0 + i) * L + l0 + tx] = f2bf(tile[tx][i]);
}

// -------- Q projection: C=A@B^T, f32 in, bf16 out; 32x128 tile, 4 waves --------
__global__ __launch_bounds__(256) void kn_qproj(const float* __restrict__ A,
                                                const float* __restrict__ B,
                                                unsigned short* __restrict__ C,
                                                int N, int K, int gxs) {
    constexpr int TM = 32;
    constexpr int MF = 2, NF = 2;          // WM=1 (4 N-waves? no): use WM=1,WN=4: MF=2,NF=2
    constexpr int CHA = TM * 8;            // 256 A-chunks
    constexpr int CPT = (CHA + 1024) / 256;// 5 chunks/thread
    constexpr int BUFU = TM * 64 + 128 * 64;
    __shared__ __align__(16) char smem_raw[2 * BUFU * 2 > TM * 132 * 4 ? 2 * BUFU * 2 : TM * 132 * 4];
    unsigned short* base = (unsigned short*)smem_raw;
    float* st = (float*)smem_raw;

    int tid = threadIdx.x;
    int t = blockIdx.x;
    int by = t >> gxs;
    int bx = t & ((1 << gxs) - 1);
    const float* Ab = A + (size_t)by * TM * K;
    const float* Bb = B + (size_t)bx * 128 * K;

    int lane = tid & 63;
    int wid = tid >> 6;                    // 0..3 -> N-wave (cols wid*32)
    int lr = lane & 15;
    int lg = lane >> 4;
    int xoff = (lane & 7) << 3;

    f32x4 rv[CPT][2];
    f32x4 acc[MF][NF] = {};

    auto LOAD = [&](int k0) {
#pragma unroll
        for (int c = 0; c < CPT; ++c) {
            int ch = c * 256 + tid;
            const float* src;
            if (ch < CHA) { int row = ch >> 3; src = Ab + (size_t)row * K + k0 + (ch & 7) * 8; }
            else { int bc = ch - CHA; int row = bc >> 3; src = Bb + (size_t)row * K + k0 + (bc & 7) * 8; }
            rv[c][0] = *(const f32x4*)src;
            rv[c][1] = *(const f32x4*)(src + 4);
        }
    };
    auto WRITE = [&](int buf) {
        unsigned short* dA = base + buf * BUFU;
        unsigned short* dB = dA + TM * 64;
#pragma unroll
        for (int c = 0; c < CPT; ++c) {
            int ch = c * 256 + tid;
            u16x8 o;
#pragma unroll
            for (int j = 0; j < 4; ++j) { o[j] = f2bf(rv[c][0][j]); o[4 + j] = f2bf(rv[c][1][j]); }
            if (ch < CHA) {
                int row = ch >> 3; int sl = (ch & 7) ^ (row & 7);
                *(u16x8*)&dA[row * 64 + sl * 8] = o;
            } else {
                int bc = ch - CHA; int row = bc >> 3; int sl = (bc & 7) ^ (row & 7);
                *(u16x8*)&dB[row * 64 + sl * 8] = o;
            }
        }
    };
    auto COMPUTE = [&](int buf) {
        unsigned short* pA = base + buf * BUFU;
        unsigned short* pB = pA + TM * 64;
#pragma unroll
        for (int kk = 0; kk < 2; ++kk) {
            int kb = (kk * 32 + lg * 8) ^ xoff;
            bf16x8 af[MF], bfr[NF];
#pragma unroll
            for (int m = 0; m < MF; ++m)
                af[m] = *(const bf16x8*)&pA[(m * 16 + lr) * 64 + kb];
#pragma unroll
            for (int n = 0; n < NF; ++n)
                bfr[n] = *(const bf16x8*)&pB[(wid * 32 + n * 16 + lr) * 64 + kb];
#pragma unroll
            for (int m = 0; m < MF; ++m)
#pragma unroll
                for (int n = 0; n < NF; ++n)
                    acc[m][n] = __builtin_amdgcn_mfma_f32_16x16x32_bf16(af[m], bfr[n], acc[m][n], 0, 0, 0);
        }
    };

    int nt = K / 64;
    LOAD(0); WRITE(0);
    __syncthreads();
    int buf = 0;
    for (int tt = 0; tt < nt; ++tt) {
        if (tt + 1 < nt) LOAD((tt + 1) * 64);
        COMPUTE(buf);
        if (tt + 1 < nt) WRITE(buf ^ 1);
        __syncthreads();
        buf ^= 1;
    }

#pragma unroll
    for (int m = 0; m < MF; ++m) {
        int r0 = m * 16 + lg * 4;
#pragma unroll
        for (int n = 0; n < NF; ++n) {
            int c0 = wid * 32 + n * 16 + lr;
#pragma unroll
            for (int j = 0; j < 4; ++j)
                st[(r0 + j) * 132 + c0] = acc[m][n][j];
        }
    }
    __syncthreads();
    int r  = tid >> 3;                     // 0..31
    int c0 = (tid & 7) * 16;
    size_t grow = (size_t)(by * TM + r) * N + bx * 128 + c0;
#pragma unroll
    for (int g = 0; g < 2; ++g) {
        f32x4 a = *(const f32x4*)&st[r * 132 + c0 + g * 8];
        f32x4 b = *(const f32x4*)&st[r * 132 + c0 + g * 8 + 4];
        u16x8 o;
#pragma unroll
        for (int j = 0; j < 4; ++j) { o[j] = f2bf(a[j]); o[4 + j] = f2bf(b[j]); }
        *(u16x8*)&C[grow + g * 8] = o;
    }
}

// -------- K projection: Kbf = Hbf @ Wk^T; A bf16 via gload_lds, B f32 reg-staged.
//          64x128 tile, BK=64, 4 waves (2M x 2N, wave-tile 32x64). --------
__global__ __launch_bounds__(256) void kn_kproj(const unsigned short* __restrict__ A,
                                                const float* __restrict__ B,
                                                unsigned short* __restrict__ C,
                                                int N, int K, int gxs) {
    __shared__ __align__(16) char smem_raw[64 * 132 * 4];    // >= 24KB tiles, 33792 epi
    unsigned short* sA = (unsigned short*)smem_raw;           // 64x64 u16 = 8KB
    unsigned short* sB = sA + 64 * 64;                        // 128x64 u16 = 16KB
    float* st = (float*)smem_raw;

    int tid = threadIdx.x;
    int t = blockIdx.x;
    int by = t >> gxs;
    int bx = t & ((1 << gxs) - 1);
    const unsigned short* Ab = A + (size_t)by * 64 * K;
    const float* Bb = B + (size_t)bx * 128 * K;

    int lane = tid & 63;
    int wid = tid >> 6;
    int wr = wid >> 1, wc = wid & 1;
    int lr = lane & 15;
    int lg = lane >> 4;
    int xoff = (lane & 7) << 3;

    f32x4 acc[2][4] = {};

    for (int k0 = 0; k0 < K; k0 += 64) {
        // A: 512 chunks via gload_lds (pre-swizzled source, linear dest)
#pragma unroll
        for (int c = 0; c < 2; ++c) {
            int ch = c * 256 + tid;
            int row = ch >> 3;
            int g8 = (ch & 7) ^ (row & 7);
            gload_lds16(Ab + (size_t)row * K + k0 + g8 * 8, sA + ch * 8);
        }
        // B: 1024 chunks f32 -> bf16 reg-staged, swizzled ds_write
#pragma unroll
        for (int c = 0; c < 4; ++c) {
            int ch = c * 256 + tid;
            int row = ch >> 3;
            const float* src = Bb + (size_t)row * K + k0 + (ch & 7) * 8;
            f32x4 v0 = *(const f32x4*)src;
            f32x4 v1 = *(const f32x4*)(src + 4);
            u16x8 o;
#pragma unroll
            for (int j = 0; j < 4; ++j) { o[j] = f2bf(v0[j]); o[4 + j] = f2bf(v1[j]); }
            int sl = (ch & 7) ^ (row & 7);
            *(u16x8*)&sB[row * 64 + sl * 8] = o;
        }
        __syncthreads();
#pragma unroll
        for (int kk = 0; kk < 2; ++kk) {
            int kb = (kk * 32 + lg * 8) ^ xoff;
            bf16x8 af[2], bfr[4];
#pragma unroll
            for (int m = 0; m < 2; ++m)
                af[m] = *(const bf16x8*)&sA[(wr * 32 + m * 16 + lr) * 64 + kb];
#pragma unroll
            for (int n = 0; n < 4; ++n)
                bfr[n] = *(const bf16x8*)&sB[(wc * 64 + n * 16 + lr) * 64 + kb];
#pragma unroll
            for (int m = 0; m < 2; ++m)
#pragma unroll
                for (int n = 0; n < 4; ++n)
                    acc[m][n] = __builtin_amdgcn_mfma_f32_16x16x32_bf16(af[m], bfr[n], acc[m][n], 0, 0, 0);
        }
        __syncthreads();
    }

    // epilogue: waves write disjoint st rows, then coalesced bf16 stores
#pragma unroll
    for (int m = 0; m < 2; ++m) {
        int r0 = wr * 32 + m * 16 + lg * 4;
#pragma unroll
        for (int n = 0; n < 4; ++n) {
            int c0 = wc * 64 + n * 16 + lr;
#pragma unroll
            for (int j = 0; j < 4; ++j)
                st[(r0 + j) * 132 + c0] = acc[m][n][j];
        }
    }
    __syncthreads();
    int r  = tid >> 2;                     // 0..63
    int c0 = (tid & 3) * 32;
    size_t grow = (size_t)(by * 64 + r) * N + bx * 128 + c0;
#pragma unroll
    for (int g = 0; g < 4; ++g) {
        f32x4 a = *(const f32x4*)&st[r * 132 + c0 + g * 8];
        f32x4 b = *(const f32x4*)&st[r * 132 + c0 + g * 8 + 4];
        u16x8 o;
#pragma unroll
        for (int j = 0; j < 4; ++j) { o[j] = f2bf(a[j]); o[4 + j] = f2bf(b[j]); }
        *(u16x8*)&C[grow + g * 8] = o;
    }
}

// ------- S-GEMM (R10 best): 256x128, BK=64, 8 waves, single-buffer; epilogue stores
//         exp(s) bf16 and atomically accumulates f32 row sums. -------
__global__ __launch_bounds__(512) void kn_sgemm(const unsigned short* __restrict__ A,
                                                const unsigned short* __restrict__ B,
                                                unsigned short* __restrict__ C,
                                                float* __restrict__ rowsum,
                                                int N, int K, int Trows,
                                                long batchA, long batchB, long batchC,
                                                float scale, int gxs) {
    __shared__ __align__(16) char smem_raw[49152];
    unsigned short* base = (unsigned short*)smem_raw;
    float* st = (float*)smem_raw;

    int tid = threadIdx.x;
    int wg = blockIdx.x;
    int bz = wg & 7;
    int t = wg >> 3;
    int by = t >> gxs;
    int bx = t & ((1 << gxs) - 1);

    const unsigned short* Ab = A + (size_t)bz * batchA + (size_t)by * 256 * K;
    const unsigned short* Bb = B + (size_t)bz * batchB + (size_t)bx * 128 * K;
    unsigned short* Cb = C + (size_t)bz * batchC;
    float* rs = rowsum + (size_t)bz * Trows;

    int lane = tid & 63;
    int wid = tid >> 6;
    int wr = wid >> 1, wc = wid & 1;
    int lr = lane & 15;
    int lg = lane >> 4;
    int xoff = (lane & 7) << 3;

    f32x4 acc[4][4] = {};

    for (int k0 = 0; k0 < K; k0 += 64) {
#pragma unroll
        for (int c = 0; c < 6; ++c) {
            int ch = c * 512 + tid;
            if (ch < 2048) {
                int row = ch >> 3;
                int g8 = (ch & 7) ^ (row & 7);
                gload_lds16(Ab + (size_t)row * K + k0 + g8 * 8, base + ch * 8);
            } else {
                int bc = ch - 2048;
                int row = bc >> 3;
                int g8 = (bc & 7) ^ (row & 7);
                gload_lds16(Bb + (size_t)row * K + k0 + g8 * 8, base + 16384 + bc * 8);
            }
        }
        __syncthreads();
#pragma unroll
        for (int kk = 0; kk < 2; ++kk) {
            int kb = (kk * 32 + lg * 8) ^ xoff;
            bf16x8 af[4], bfr[4];
#pragma unroll
            for (int m = 0; m < 4; ++m)
                af[m] = *(const bf16x8*)&base[(wr * 64 + m * 16 + lr) * 64 + kb];
#pragma unroll
            for (int n = 0; n < 4; ++n)
                bfr[n] = *(const bf16x8*)&base[16384 + (wc * 64 + n * 16 + lr) * 64 + kb];
#pragma unroll
            for (int m = 0; m < 4; ++m)
#pragma unroll
                for (int n = 0; n < 4; ++n)
                    acc[m][n] = __builtin_amdgcn_mfma_f32_16x16x32_bf16(af[m], bfr[n], acc[m][n], 0, 0, 0);
        }
        __syncthreads();
    }

#pragma unroll
    for (int q = 0; q < 4; ++q) {
        if (wr == q) {
#pragma unroll
            for (int m = 0; m < 4; ++m) {
                int rl = m * 16 + lg * 4;
#pragma unroll
                for (int n = 0; n < 4; ++n) {
                    int col = wc * 64 + n * 16 + lr;
#pragma unroll
                    for (int j = 0; j < 4; ++j)
                        st[(rl + j) * 132 + col] = acc[m][n][j] * scale;
                }
            }
        }
        __syncthreads();
        int r = tid >> 3;
        int c0 = (tid & 7) * 16;
        int grow_r = by * 256 + q * 64 + r;
        size_t grow = (size_t)grow_r * N + bx * 128 + c0;
        float psum = 0.f;
#pragma unroll
        for (int g = 0; g < 2; ++g) {
            f32x4 a = *(const f32x4*)&st[r * 132 + c0 + g * 8];
            f32x4 b = *(const f32x4*)&st[r * 132 + c0 + g * 8 + 4];
            u16x8 o;
#pragma unroll
            for (int j = 0; j < 4; ++j) {
                o[j]     = f2bf(__expf(a[j]));
                o[4 + j] = f2bf(__expf(b[j]));
                psum += bf2f(o[j]) + bf2f(o[4 + j]);
            }
            *(u16x8*)&Cb[grow + g * 8] = o;
        }
        psum += __shfl_xor(psum, 1);
        psum += __shfl_xor(psum, 2);
        psum += __shfl_xor(psum, 4);
        if ((tid & 7) == 0)
            atomicAdd(&rs[grow_r], psum);
        __syncthreads();
    }
}

// ------- PV (R10 best): 256x128, BK=64, 8 waves, 3-buf LDS, register-dbuf frags.
//         Epilogue divides by rowsum. -------
__global__ __launch_bounds__(512) void kn_pv(const unsigned short* __restrict__ A,
                                             const unsigned short* __restrict__ B,
                                             float* __restrict__ C,
                                             const float* __restrict__ rowsum,
                                             int N, int K, int Trows,
                                             long batchA, long batchB, long batchC,
                                             int gxs) {
    __shared__ __align__(16) char smem_raw[3 * 49152];       // 144KB
    unsigned short* base = (unsigned short*)smem_raw;
    float* st = (float*)smem_raw;

    int tid = threadIdx.x;
    int wg = blockIdx.x;
    int bz = wg & 7;
    int t = wg >> 3;
    int by = t >> gxs;
    int bx = t & ((1 << gxs) - 1);

    const unsigned short* Ab = A + (size_t)bz * batchA + (size_t)by * 256 * K;
    const unsigned short* Bb = B + (size_t)bz * batchB + (size_t)bx * 128 * K;
    float* Cb = C + (size_t)bz * batchC;
    const float* rs = rowsum + (size_t)bz * Trows;

    int lane = tid & 63;
    int wid = tid >> 6;
    int wr = wid >> 1, wc = wid & 1;
    int lr = lane & 15;
    int lg = lane >> 4;
    int xoff = (lane & 7) << 3;

    f32x4 acc[4][4] = {};
    bf16x8 fA0[4], fB0[4], fA1[4], fB1[4];

    auto STAGE_HALF = [&](int buf, int k0, int half) {
        unsigned short* dA = base + buf * 24576;
        unsigned short* dB = dA + 16384;
#pragma unroll
        for (int c = 0; c < 3; ++c) {
            int ch = half * 1536 + c * 512 + tid;
            if (ch < 2048) {
                int row = ch >> 3;
                int g8 = (ch & 7) ^ (row & 7);
                gload_lds16(Ab + (size_t)row * K + k0 + g8 * 8, dA + ch * 8);
            } else {
                int bc = ch - 2048;
                int row = bc >> 3;
                int g8 = (bc & 7) ^ (row & 7);
                gload_lds16(Bb + (size_t)row * K + k0 + g8 * 8, dB + bc * 8);
            }
        }
    };
    auto LDFRAG = [&](int buf, int kk, bf16x8* fa, bf16x8* fb) {
        unsigned short* pA = base + buf * 24576;
        unsigned short* pB = pA + 16384;
        int kb = (kk * 32 + lg * 8) ^ xoff;
#pragma unroll
        for (int m = 0; m < 4; ++m)
            fa[m] = *(const bf16x8*)&pA[(wr * 64 + m * 16 + lr) * 64 + kb];
#pragma unroll
        for (int n = 0; n < 4; ++n)
            fb[n] = *(const bf16x8*)&pB[(wc * 64 + n * 16 + lr) * 64 + kb];
    };

    int nt = K / 64;                           // 32
    STAGE_HALF(0, 0, 0);   STAGE_HALF(0, 0, 1);
    STAGE_HALF(1, 64, 0);  STAGE_HALF(1, 64, 1);
    asm volatile("s_waitcnt vmcnt(6)" ::: "memory");
    __builtin_amdgcn_s_barrier();
    LDFRAG(0, 0, fA0, fB0);

    int cur = 0;
    for (int tt = 0; tt < nt; ++tt) {
        int nb  = (cur >= 1) ? cur - 1 : 2;
        int nxt = (cur == 2) ? 0 : cur + 1;
        if (tt + 2 < nt) STAGE_HALF(nb, (tt + 2) * 64, 0);
        LDFRAG(cur, 1, fA1, fB1);
        __builtin_amdgcn_sched_barrier(0);
        __builtin_amdgcn_s_setprio(1);
#pragma unroll
        for (int m = 0; m < 4; ++m)
#pragma unroll
            for (int n = 0; n < 4; ++n)
                acc[m][n] = __builtin_amdgcn_mfma_f32_16x16x32_bf16(fA0[m], fB0[n], acc[m][n], 0, 0, 0);
        __builtin_amdgcn_s_setprio(0);
        __builtin_amdgcn_sched_barrier(0);
        if (tt + 2 < nt) STAGE_HALF(nb, (tt + 2) * 64, 1);
        __builtin_amdgcn_sched_barrier(0);
        __builtin_amdgcn_s_setprio(1);
#pragma unroll
        for (int m = 0; m < 4; ++m)
#pragma unroll
            for (int n = 0; n < 4; ++n)
                acc[m][n] = __builtin_amdgcn_mfma_f32_16x16x32_bf16(fA1[m], fB1[n], acc[m][n], 0, 0, 0);
        __builtin_amdgcn_s_setprio(0);
        __builtin_amdgcn_sched_barrier(0);
        if (tt + 1 < nt) {
            if (tt + 2 < nt) asm volatile("s_waitcnt vmcnt(6)" ::: "memory");
            else             asm volatile("s_waitcnt vmcnt(0)" ::: "memory");
            LDFRAG(nxt, 0, fA0, fB0);
            __builtin_amdgcn_sched_barrier(0);
            __builtin_amdgcn_s_barrier();
        }
        cur = nxt;
    }
    __syncthreads();

#pragma unroll
    for (int q = 0; q < 4; ++q) {
        if (wr == q) {
#pragma unroll
            for (int m = 0; m < 4; ++m) {
                int rl = m * 16 + lg * 4;
#pragma unroll
                for (int n = 0; n < 4; ++n) {
                    int col = wc * 64 + n * 16 + lr;
#pragma unroll
                    for (int j = 0; j < 4; ++j)
                        st[(rl + j) * 132 + col] = acc[m][n][j];
                }
            }
        }
        __syncthreads();
        int r = tid >> 3;
        int c0 = (tid & 7) * 16;
        float inv = 1.0f / rs[by * 256 + q * 64 + r];
        size_t grow = (size_t)(by * 256 + q * 64 + r) * N + bx * 128 + c0;
#pragma unroll
        for (int g = 0; g < 4; ++g) {
            f32x4 v = *(const f32x4*)&st[r * 132 + c0 + g * 4];
#pragma unroll
            for (int j = 0; j < 4; ++j) v[j] *= inv;
            *(f32x4*)&Cb[grow + g * 4] = v;
        }
        __syncthreads();
    }
}

extern "C" void kernel_launch(void* const* d_in, const int* in_sizes, int n_in,
                              void* d_out, int out_size, void* d_ws, size_t ws_size,
                              hipStream_t stream) {
    constexpr int B = 8, L = 2048, T = 1024, Dh = 1024, Dg = 768, Dp = 256;
    const float* H  = (const float*)d_in[0];
    const float* G  = (const float*)d_in[1];
    const float* Wq = (const float*)d_in[2];
    const float* Wk = (const float*)d_in[3];
    float* Z = (float*)d_out;

    unsigned short* Qbf = (unsigned short*)d_ws;             // B*T*Dp  = 2M
    unsigned short* Kbf = Qbf + (size_t)B * T * Dp;          // B*L*Dp  = 4M
    unsigned short* HT  = Kbf + (size_t)B * L * Dp;          // B*Dh*L  = 16M
    unsigned short* S   = HT  + (size_t)B * Dh * L;          // B*T*L   = 16M
    unsigned short* Hbf = S   + (size_t)B * T * L;           // B*L*Dh  = 16M
    float* rowsum = (float*)(Hbf + (size_t)B * L * Dh);      // B*T f32

    hipMemsetAsync(rowsum, 0, (size_t)B * T * sizeof(float), stream);

    // HT + Hbf from H
    kn_transp<<<dim3(Dh / 64, L / 64, B), dim3(64, 4), 0, stream>>>(H, HT, Hbf, L, Dh);

    // Q = G @ Wq^T  [8192,256], K=768; 32x128 tiles -> 512 blocks
    kn_qproj<<<(B * T / 32) * (Dp / 128), 256, 0, stream>>>(G, Wq, Qbf, Dp, Dg, 1);

    // K = Hbf @ Wk^T  [16384,256], K=1024; 64x128 tiles -> 512 blocks
    kn_kproj<<<(B * L / 64) * (Dp / 128), 256, 0, stream>>>(Hbf, Wk, Kbf, Dp, Dh, 1);

    // Sexp = exp(Q@K^T/16): 256x128 tiles -> 512 blocks
    kn_sgemm<<<(T / 256) * (L / 128) * B, 512, 0, stream>>>
        (Qbf, Kbf, S, rowsum, L, Dp, T, (long)T * Dp, (long)L * Dp, (long)T * L, 0.0625f, 4);

    // Z = (Sexp @ HT^T)/rowsum: 256x128 tiles -> 256 blocks
    kn_pv<<<(T / 256) * (Dh / 128) * B, 512, 0, stream>>>
        (S, HT, Z, rowsum, Dh, L, T, (long)T * L, (long)Dh * L, (long)T * Dh, 3);
}

// Round 15
// 135.440 us; speedup vs baseline: 1.1354x; 1.0476x over previous
//
#include <hip/hip_runtime.h>
#include <hip/hip_bf16.h>
#include <type_traits>

// Dims: B=8, L=2048, T=1024, Dh=1024, Dg=768, Dp=256
// Pipeline: Wqbf,Wkbf=cast(W); [HT,Hbf]=transpose+cast(H); Q=G@Wqbf^T; K=Hbf@Wkbf^T;
//           Sexp=exp(Q@K^T/16)[+rowsum]; Z=(Sexp@HT^T)/rowsum
// R15: vectorized transp (32B loads / 16B stores); all-bf16 kproj; qproj B via gload.
//      PV/sgemm = R10/R14 measured-best, untouched.
// Workspace (u16): Qbf 2M | Kbf 4M | HT 16M | S 16M | Hbf 16M | Wqbf | Wkbf | rowsum f32

typedef float    f32x4  __attribute__((ext_vector_type(4)));
typedef __bf16   bf16x8 __attribute__((ext_vector_type(8)));
typedef unsigned short u16x8 __attribute__((ext_vector_type(8)));

__device__ __forceinline__ unsigned short f2bf(float f) {
    union { __bf16 b; unsigned short u; } c;
    c.b = (__bf16)f;                       // native RNE cvt
    return c.u;
}
__device__ __forceinline__ float bf2f(unsigned short u) {
    union { unsigned u; float f; } x; x.u = ((unsigned)u) << 16;
    return x.f;
}
__device__ __forceinline__ void gload_lds16(const unsigned short* g, unsigned short* l) {
    __builtin_amdgcn_global_load_lds(
        (const __attribute__((address_space(1))) void*)g,
        (__attribute__((address_space(3))) void*)l, 16, 0, 0);
}

// ---------------- cast Wq and Wk to bf16 (one launch) ----------------
__global__ __launch_bounds__(256) void kn_castw(const float* __restrict__ Wq,
                                                const float* __restrict__ Wk,
                                                unsigned short* __restrict__ Wqbf,
                                                unsigned short* __restrict__ Wkbf,
                                                int nq8, int nk8) {
    int i = blockIdx.x * 256 + threadIdx.x;
    const float* src;
    unsigned short* dst;
    int idx;
    if (i < nq8) { idx = i; src = Wq; dst = Wqbf; }
    else { idx = i - nq8; if (idx >= nk8) return; src = Wk; dst = Wkbf; }
    f32x4 a = *(const f32x4*)(src + (size_t)idx * 8);
    f32x4 b = *(const f32x4*)(src + (size_t)idx * 8 + 4);
    u16x8 o;
#pragma unroll
    for (int j = 0; j < 4; ++j) { o[j] = f2bf(a[j]); o[4 + j] = f2bf(b[j]); }
    *(u16x8*)(dst + (size_t)idx * 8) = o;
}

// ------ transpose + dual cast, vectorized: H [L,Dh] f32 -> HT [Dh,L] + Hbf [L,Dh] ------
// 64x64 tile, 256 thr. Loads 32B/lane; both stores u16x8 (16B/lane). LDS 2-way max.
__global__ __launch_bounds__(256) void kn_transp(const float* __restrict__ H,
                                                 unsigned short* __restrict__ HT,
                                                 unsigned short* __restrict__ Hbf,
                                                 int L, int D) {
    __shared__ float tile[64][65];
    int b = blockIdx.z;
    const float* src = H + (size_t)b * L * D;
    unsigned short* dstT = HT + (size_t)b * L * D;
    unsigned short* dstN = Hbf + (size_t)b * L * D;
    int l0 = blockIdx.y * 64, d0 = blockIdx.x * 64;
    int rh = threadIdx.x >> 3;            // 0..31
    int c8 = (threadIdx.x & 7) * 8;       // 0..56

#pragma unroll
    for (int i = 0; i < 2; ++i) {
        int r = rh + i * 32;
        const float* p = &src[(size_t)(l0 + r) * D + d0 + c8];
        f32x4 v0 = *(const f32x4*)p;
        f32x4 v1 = *(const f32x4*)(p + 4);
        u16x8 o;
#pragma unroll
        for (int j = 0; j < 4; ++j) {
            o[j] = f2bf(v0[j]); o[4 + j] = f2bf(v1[j]);
            tile[r][c8 + j] = v0[j];
            tile[r][c8 + 4 + j] = v1[j];
        }
        *(u16x8*)&dstN[(size_t)(l0 + r) * D + d0 + c8] = o;
    }
    __syncthreads();
#pragma unroll
    for (int i = 0; i < 2; ++i) {
        int d = rh + i * 32;
        u16x8 o;
#pragma unroll
        for (int j = 0; j < 8; ++j) o[j] = f2bf(tile[c8 + j][d]);
        *(u16x8*)&dstT[(size_t)(d0 + d) * L + l0 + c8] = o;
    }
}

// -------- Q projection: Q = G @ Wqbf^T; A f32 reg-staged (1 chunk/thr), B bf16 gload.
//          32x128 tile, BK=64, 4 waves (N-split). --------
__global__ __launch_bounds__(256) void kn_qproj(const float* __restrict__ A,
                                                const unsigned short* __restrict__ B,
                                                unsigned short* __restrict__ C,
                                                int N, int K, int gxs) {
    __shared__ __align__(16) char smem_raw[20480];           // sA 4KB + sB 16KB; st 16896
    unsigned short* sA = (unsigned short*)smem_raw;           // 32x64 u16
    unsigned short* sB = sA + 32 * 64;                        // 128x64 u16
    float* st = (float*)smem_raw;

    int tid = threadIdx.x;
    int t = blockIdx.x;
    int by = t >> gxs;
    int bx = t & ((1 << gxs) - 1);
    const float* Ab = A + (size_t)by * 32 * K;
    const unsigned short* Bb = B + (size_t)bx * 128 * K;

    int lane = tid & 63;
    int wid = tid >> 6;                    // N-wave: cols wid*32
    int lr = lane & 15;
    int lg = lane >> 4;
    int xoff = (lane & 7) << 3;

    f32x4 acc[2][2] = {};

    for (int k0 = 0; k0 < K; k0 += 64) {
        // B: 1024 bf16 chunks via gload_lds (pre-swizzled source)
#pragma unroll
        for (int c = 0; c < 4; ++c) {
            int ch = c * 256 + tid;
            int row = ch >> 3;
            int g8 = (ch & 7) ^ (row & 7);
            gload_lds16(Bb + (size_t)row * K + k0 + g8 * 8, sB + ch * 8);
        }
        // A: 256 chunks f32 -> bf16 reg-staged, swizzled ds_write
        {
            int ch = tid;
            int row = ch >> 3;
            const float* srcp = Ab + (size_t)row * K + k0 + (ch & 7) * 8;
            f32x4 v0 = *(const f32x4*)srcp;
            f32x4 v1 = *(const f32x4*)(srcp + 4);
            u16x8 o;
#pragma unroll
            for (int j = 0; j < 4; ++j) { o[j] = f2bf(v0[j]); o[4 + j] = f2bf(v1[j]); }
            int sl = (ch & 7) ^ (row & 7);
            *(u16x8*)&sA[row * 64 + sl * 8] = o;
        }
        __syncthreads();
#pragma unroll
        for (int kk = 0; kk < 2; ++kk) {
            int kb = (kk * 32 + lg * 8) ^ xoff;
            bf16x8 af[2], bfr[2];
#pragma unroll
            for (int m = 0; m < 2; ++m)
                af[m] = *(const bf16x8*)&sA[(m * 16 + lr) * 64 + kb];
#pragma unroll
            for (int n = 0; n < 2; ++n)
                bfr[n] = *(const bf16x8*)&sB[(wid * 32 + n * 16 + lr) * 64 + kb];
#pragma unroll
            for (int m = 0; m < 2; ++m)
#pragma unroll
                for (int n = 0; n < 2; ++n)
                    acc[m][n] = __builtin_amdgcn_mfma_f32_16x16x32_bf16(af[m], bfr[n], acc[m][n], 0, 0, 0);
        }
        __syncthreads();
    }

#pragma unroll
    for (int m = 0; m < 2; ++m) {
        int r0 = m * 16 + lg * 4;
#pragma unroll
        for (int n = 0; n < 2; ++n) {
            int c0 = wid * 32 + n * 16 + lr;
#pragma unroll
            for (int j = 0; j < 4; ++j)
                st[(r0 + j) * 132 + c0] = acc[m][n][j];
        }
    }
    __syncthreads();
    int r  = tid >> 3;                     // 0..31
    int c0 = (tid & 7) * 16;
    size_t grow = (size_t)(by * 32 + r) * N + bx * 128 + c0;
#pragma unroll
    for (int g = 0; g < 2; ++g) {
        f32x4 a = *(const f32x4*)&st[r * 132 + c0 + g * 8];
        f32x4 b = *(const f32x4*)&st[r * 132 + c0 + g * 8 + 4];
        u16x8 o;
#pragma unroll
        for (int j = 0; j < 4; ++j) { o[j] = f2bf(a[j]); o[4 + j] = f2bf(b[j]); }
        *(u16x8*)&C[grow + g * 8] = o;
    }
}

// -------- K projection: Kbf = Hbf @ Wkbf^T; ALL-bf16 via gload_lds.
//          64x128 tile, BK=64, 4 waves (2M x 2N). --------
__global__ __launch_bounds__(256) void kn_kproj(const unsigned short* __restrict__ A,
                                                const unsigned short* __restrict__ B,
                                                unsigned short* __restrict__ C,
                                                int N, int K, int gxs) {
    __shared__ __align__(16) char smem_raw[64 * 132 * 4];    // tiles 24KB; epi 33792
    unsigned short* sA = (unsigned short*)smem_raw;           // 64x64 u16 = 8KB
    unsigned short* sB = sA + 64 * 64;                        // 128x64 u16 = 16KB
    float* st = (float*)smem_raw;

    int tid = threadIdx.x;
    int t = blockIdx.x;
    int by = t >> gxs;
    int bx = t & ((1 << gxs) - 1);
    const unsigned short* Ab = A + (size_t)by * 64 * K;
    const unsigned short* Bb = B + (size_t)bx * 128 * K;

    int lane = tid & 63;
    int wid = tid >> 6;
    int wr = wid >> 1, wc = wid & 1;
    int lr = lane & 15;
    int lg = lane >> 4;
    int xoff = (lane & 7) << 3;

    f32x4 acc[2][4] = {};

    for (int k0 = 0; k0 < K; k0 += 64) {
#pragma unroll
        for (int c = 0; c < 2; ++c) {          // A: 512 chunks
            int ch = c * 256 + tid;
            int row = ch >> 3;
            int g8 = (ch & 7) ^ (row & 7);
            gload_lds16(Ab + (size_t)row * K + k0 + g8 * 8, sA + ch * 8);
        }
#pragma unroll
        for (int c = 0; c < 4; ++c) {          // B: 1024 chunks
            int ch = c * 256 + tid;
            int row = ch >> 3;
            int g8 = (ch & 7) ^ (row & 7);
            gload_lds16(Bb + (size_t)row * K + k0 + g8 * 8, sB + ch * 8);
        }
        __syncthreads();
#pragma unroll
        for (int kk = 0; kk < 2; ++kk) {
            int kb = (kk * 32 + lg * 8) ^ xoff;
            bf16x8 af[2], bfr[4];
#pragma unroll
            for (int m = 0; m < 2; ++m)
                af[m] = *(const bf16x8*)&sA[(wr * 32 + m * 16 + lr) * 64 + kb];
#pragma unroll
            for (int n = 0; n < 4; ++n)
                bfr[n] = *(const bf16x8*)&sB[(wc * 64 + n * 16 + lr) * 64 + kb];
#pragma unroll
            for (int m = 0; m < 2; ++m)
#pragma unroll
                for (int n = 0; n < 4; ++n)
                    acc[m][n] = __builtin_amdgcn_mfma_f32_16x16x32_bf16(af[m], bfr[n], acc[m][n], 0, 0, 0);
        }
        __syncthreads();
    }

#pragma unroll
    for (int m = 0; m < 2; ++m) {
        int r0 = wr * 32 + m * 16 + lg * 4;
#pragma unroll
        for (int n = 0; n < 4; ++n) {
            int c0 = wc * 64 + n * 16 + lr;
#pragma unroll
            for (int j = 0; j < 4; ++j)
                st[(r0 + j) * 132 + c0] = acc[m][n][j];
        }
    }
    __syncthreads();
    int r  = tid >> 2;                     // 0..63
    int c0 = (tid & 3) * 32;
    size_t grow = (size_t)(by * 64 + r) * N + bx * 128 + c0;
#pragma unroll
    for (int g = 0; g < 4; ++g) {
        f32x4 a = *(const f32x4*)&st[r * 132 + c0 + g * 8];
        f32x4 b = *(const f32x4*)&st[r * 132 + c0 + g * 8 + 4];
        u16x8 o;
#pragma unroll
        for (int j = 0; j < 4; ++j) { o[j] = f2bf(a[j]); o[4 + j] = f2bf(b[j]); }
        *(u16x8*)&C[grow + g * 8] = o;
    }
}

// ------- S-GEMM (unchanged R14): 256x128, BK=64, 8 waves; exp + rowsum epilogue -------
__global__ __launch_bounds__(512) void kn_sgemm(const unsigned short* __restrict__ A,
                                                const unsigned short* __restrict__ B,
                                                unsigned short* __restrict__ C,
                                                float* __restrict__ rowsum,
                                                int N, int K, int Trows,
                                                long batchA, long batchB, long batchC,
                                                float scale, int gxs) {
    __shared__ __align__(16) char smem_raw[49152];
    unsigned short* base = (unsigned short*)smem_raw;
    float* st = (float*)smem_raw;

    int tid = threadIdx.x;
    int wg = blockIdx.x;
    int bz = wg & 7;
    int t = wg >> 3;
    int by = t >> gxs;
    int bx = t & ((1 << gxs) - 1);

    const unsigned short* Ab = A + (size_t)bz * batchA + (size_t)by * 256 * K;
    const unsigned short* Bb = B + (size_t)bz * batchB + (size_t)bx * 128 * K;
    unsigned short* Cb = C + (size_t)bz * batchC;
    float* rs = rowsum + (size_t)bz * Trows;

    int lane = tid & 63;
    int wid = tid >> 6;
    int wr = wid >> 1, wc = wid & 1;
    int lr = lane & 15;
    int lg = lane >> 4;
    int xoff = (lane & 7) << 3;

    f32x4 acc[4][4] = {};

    for (int k0 = 0; k0 < K; k0 += 64) {
#pragma unroll
        for (int c = 0; c < 6; ++c) {
            int ch = c * 512 + tid;
            if (ch < 2048) {
                int row = ch >> 3;
                int g8 = (ch & 7) ^ (row & 7);
                gload_lds16(Ab + (size_t)row * K + k0 + g8 * 8, base + ch * 8);
            } else {
                int bc = ch - 2048;
                int row = bc >> 3;
                int g8 = (bc & 7) ^ (row & 7);
                gload_lds16(Bb + (size_t)row * K + k0 + g8 * 8, base + 16384 + bc * 8);
            }
        }
        __syncthreads();
#pragma unroll
        for (int kk = 0; kk < 2; ++kk) {
            int kb = (kk * 32 + lg * 8) ^ xoff;
            bf16x8 af[4], bfr[4];
#pragma unroll
            for (int m = 0; m < 4; ++m)
                af[m] = *(const bf16x8*)&base[(wr * 64 + m * 16 + lr) * 64 + kb];
#pragma unroll
            for (int n = 0; n < 4; ++n)
                bfr[n] = *(const bf16x8*)&base[16384 + (wc * 64 + n * 16 + lr) * 64 + kb];
#pragma unroll
            for (int m = 0; m < 4; ++m)
#pragma unroll
                for (int n = 0; n < 4; ++n)
                    acc[m][n] = __builtin_amdgcn_mfma_f32_16x16x32_bf16(af[m], bfr[n], acc[m][n], 0, 0, 0);
        }
        __syncthreads();
    }

#pragma unroll
    for (int q = 0; q < 4; ++q) {
        if (wr == q) {
#pragma unroll
            for (int m = 0; m < 4; ++m) {
                int rl = m * 16 + lg * 4;
#pragma unroll
                for (int n = 0; n < 4; ++n) {
                    int col = wc * 64 + n * 16 + lr;
#pragma unroll
                    for (int j = 0; j < 4; ++j)
                        st[(rl + j) * 132 + col] = acc[m][n][j] * scale;
                }
            }
        }
        __syncthreads();
        int r = tid >> 3;
        int c0 = (tid & 7) * 16;
        int grow_r = by * 256 + q * 64 + r;
        size_t grow = (size_t)grow_r * N + bx * 128 + c0;
        float psum = 0.f;
#pragma unroll
        for (int g = 0; g < 2; ++g) {
            f32x4 a = *(const f32x4*)&st[r * 132 + c0 + g * 8];
            f32x4 b = *(const f32x4*)&st[r * 132 + c0 + g * 8 + 4];
            u16x8 o;
#pragma unroll
            for (int j = 0; j < 4; ++j) {
                o[j]     = f2bf(__expf(a[j]));
                o[4 + j] = f2bf(__expf(b[j]));
                psum += bf2f(o[j]) + bf2f(o[4 + j]);
            }
            *(u16x8*)&Cb[grow + g * 8] = o;
        }
        psum += __shfl_xor(psum, 1);
        psum += __shfl_xor(psum, 2);
        psum += __shfl_xor(psum, 4);
        if ((tid & 7) == 0)
            atomicAdd(&rs[grow_r], psum);
        __syncthreads();
    }
}

// ------- PV (unchanged R10/R14 best): 256x128, BK=64, 3-buf, reg-dbuf frags -------
__global__ __launch_bounds__(512) void kn_pv(const unsigned short* __restrict__ A,
                                             const unsigned short* __restrict__ B,
                                             float* __restrict__ C,
                                             const float* __restrict__ rowsum,
                                             int N, int K, int Trows,
                                             long batchA, long batchB, long batchC,
                                             int gxs) {
    __shared__ __align__(16) char smem_raw[3 * 49152];       // 144KB
    unsigned short* base = (unsigned short*)smem_raw;
    float* st = (float*)smem_raw;

    int tid = threadIdx.x;
    int wg = blockIdx.x;
    int bz = wg & 7;
    int t = wg >> 3;
    int by = t >> gxs;
    int bx = t & ((1 << gxs) - 1);

    const unsigned short* Ab = A + (size_t)bz * batchA + (size_t)by * 256 * K;
    const unsigned short* Bb = B + (size_t)bz * batchB + (size_t)bx * 128 * K;
    float* Cb = C + (size_t)bz * batchC;
    const float* rs = rowsum + (size_t)bz * Trows;

    int lane = tid & 63;
    int wid = tid >> 6;
    int wr = wid >> 1, wc = wid & 1;
    int lr = lane & 15;
    int lg = lane >> 4;
    int xoff = (lane & 7) << 3;

    f32x4 acc[4][4] = {};
    bf16x8 fA0[4], fB0[4], fA1[4], fB1[4];

    auto STAGE_HALF = [&](int buf, int k0, int half) {
        unsigned short* dA = base + buf * 24576;
        unsigned short* dB = dA + 16384;
#pragma unroll
        for (int c = 0; c < 3; ++c) {
            int ch = half * 1536 + c * 512 + tid;
            if (ch < 2048) {
                int row = ch >> 3;
                int g8 = (ch & 7) ^ (row & 7);
                gload_lds16(Ab + (size_t)row * K + k0 + g8 * 8, dA + ch * 8);
            } else {
                int bc = ch - 2048;
                int row = bc >> 3;
                int g8 = (bc & 7) ^ (row & 7);
                gload_lds16(Bb + (size_t)row * K + k0 + g8 * 8, dB + bc * 8);
            }
        }
    };
    auto LDFRAG = [&](int buf, int kk, bf16x8* fa, bf16x8* fb) {
        unsigned short* pA = base + buf * 24576;
        unsigned short* pB = pA + 16384;
        int kb = (kk * 32 + lg * 8) ^ xoff;
#pragma unroll
        for (int m = 0; m < 4; ++m)
            fa[m] = *(const bf16x8*)&pA[(wr * 64 + m * 16 + lr) * 64 + kb];
#pragma unroll
        for (int n = 0; n < 4; ++n)
            fb[n] = *(const bf16x8*)&pB[(wc * 64 + n * 16 + lr) * 64 + kb];
    };

    int nt = K / 64;                           // 32
    STAGE_HALF(0, 0, 0);   STAGE_HALF(0, 0, 1);
    STAGE_HALF(1, 64, 0);  STAGE_HALF(1, 64, 1);
    asm volatile("s_waitcnt vmcnt(6)" ::: "memory");
    __builtin_amdgcn_s_barrier();
    LDFRAG(0, 0, fA0, fB0);

    int cur = 0;
    for (int tt = 0; tt < nt; ++tt) {
        int nb  = (cur >= 1) ? cur - 1 : 2;
        int nxt = (cur == 2) ? 0 : cur + 1;
        if (tt + 2 < nt) STAGE_HALF(nb, (tt + 2) * 64, 0);
        LDFRAG(cur, 1, fA1, fB1);
        __builtin_amdgcn_sched_barrier(0);
        __builtin_amdgcn_s_setprio(1);
#pragma unroll
        for (int m = 0; m < 4; ++m)
#pragma unroll
            for (int n = 0; n < 4; ++n)
                acc[m][n] = __builtin_amdgcn_mfma_f32_16x16x32_bf16(fA0[m], fB0[n], acc[m][n], 0, 0, 0);
        __builtin_amdgcn_s_setprio(0);
        __builtin_amdgcn_sched_barrier(0);
        if (tt + 2 < nt) STAGE_HALF(nb, (tt + 2) * 64, 1);
        __builtin_amdgcn_sched_barrier(0);
        __builtin_amdgcn_s_setprio(1);
#pragma unroll
        for (int m = 0; m < 4; ++m)
#pragma unroll
            for (int n = 0; n < 4; ++n)
                acc[m][n] = __builtin_amdgcn_mfma_f32_16x16x32_bf16(fA1[m], fB1[n], acc[m][n], 0, 0, 0);
        __builtin_amdgcn_s_setprio(0);
        __builtin_amdgcn_sched_barrier(0);
        if (tt + 1 < nt) {
            if (tt + 2 < nt) asm volatile("s_waitcnt vmcnt(6)" ::: "memory");
            else             asm volatile("s_waitcnt vmcnt(0)" ::: "memory");
            LDFRAG(nxt, 0, fA0, fB0);
            __builtin_amdgcn_sched_barrier(0);
            __builtin_amdgcn_s_barrier();
        }
        cur = nxt;
    }
    __syncthreads();

#pragma unroll
    for (int q = 0; q < 4; ++q) {
        if (wr == q) {
#pragma unroll
            for (int m = 0; m < 4; ++m) {
                int rl = m * 16 + lg * 4;
#pragma unroll
                for (int n = 0; n < 4; ++n) {
                    int col = wc * 64 + n * 16 + lr;
#pragma unroll
                    for (int j = 0; j < 4; ++j)
                        st[(rl + j) * 132 + col] = acc[m][n][j];
                }
            }
        }
        __syncthreads();
        int r = tid >> 3;
        int c0 = (tid & 7) * 16;
        float inv = 1.0f / rs[by * 256 + q * 64 + r];
        size_t grow = (size_t)(by * 256 + q * 64 + r) * N + bx * 128 + c0;
#pragma unroll
        for (int g = 0; g < 4; ++g) {
            f32x4 v = *(const f32x4*)&st[r * 132 + c0 + g * 4];
#pragma unroll
            for (int j = 0; j < 4; ++j) v[j] *= inv;
            *(f32x4*)&Cb[grow + g * 4] = v;
        }
        __syncthreads();
    }
}

extern "C" void kernel_launch(void* const* d_in, const int* in_sizes, int n_in,
                              void* d_out, int out_size, void* d_ws, size_t ws_size,
                              hipStream_t stream) {
    constexpr int B = 8, L = 2048, T = 1024, Dh = 1024, Dg = 768, Dp = 256;
    const float* H  = (const float*)d_in[0];
    const float* G  = (const float*)d_in[1];
    const float* Wq = (const float*)d_in[2];
    const float* Wk = (const float*)d_in[3];
    float* Z = (float*)d_out;

    unsigned short* Qbf  = (unsigned short*)d_ws;            // B*T*Dp  = 2M
    unsigned short* Kbf  = Qbf + (size_t)B * T * Dp;         // B*L*Dp  = 4M
    unsigned short* HT   = Kbf + (size_t)B * L * Dp;         // B*Dh*L  = 16M
    unsigned short* S    = HT  + (size_t)B * Dh * L;         // B*T*L   = 16M
    unsigned short* Hbf  = S   + (size_t)B * T * L;          // B*L*Dh  = 16M
    unsigned short* Wqbf = Hbf + (size_t)B * L * Dh;         // Dp*Dg
    unsigned short* Wkbf = Wqbf + (size_t)Dp * Dg;           // Dp*Dh
    float* rowsum = (float*)(Wkbf + (size_t)Dp * Dh);        // B*T f32

    hipMemsetAsync(rowsum, 0, (size_t)B * T * sizeof(float), stream);

    // cast Wq + Wk
    int nq8 = Dp * Dg / 8, nk8 = Dp * Dh / 8;
    kn_castw<<<(nq8 + nk8 + 255) / 256, 256, 0, stream>>>(Wq, Wk, Wqbf, Wkbf, nq8, nk8);

    // HT + Hbf from H (vectorized)
    kn_transp<<<dim3(Dh / 64, L / 64, B), dim3(256), 0, stream>>>(H, HT, Hbf, L, Dh);

    // Q = G @ Wqbf^T  [8192,256], K=768; 32x128 tiles -> 512 blocks
    kn_qproj<<<(B * T / 32) * (Dp / 128), 256, 0, stream>>>(G, Wqbf, Qbf, Dp, Dg, 1);

    // K = Hbf @ Wkbf^T  [16384,256], K=1024; 64x128 tiles -> 512 blocks
    kn_kproj<<<(B * L / 64) * (Dp / 128), 256, 0, stream>>>(Hbf, Wkbf, Kbf, Dp, Dh, 1);

    // Sexp = exp(Q@K^T/16): 256x128 tiles -> 512 blocks
    kn_sgemm<<<(T / 256) * (L / 128) * B, 512, 0, stream>>>
        (Qbf, Kbf, S, rowsum, L, Dp, T, (long)T * Dp, (long)L * Dp, (long)T * L, 0.0625f, 4);

    // Z = (Sexp @ HT^T)/rowsum: 256x128 tiles -> 256 blocks
    kn_pv<<<(T / 256) * (Dh / 128) * B, 512, 0, stream>>>
        (S, HT, Z, rowsum, Dh, L, T, (long)T * L, (long)Dh * L, (long)T * Dh, 3);
}

// Round 16
// 124.157 us; speedup vs baseline: 1.2385x; 1.0909x over previous
//
#include <hip/hip_runtime.h>
#include <hip/hip_bf16.h>
#include <type_traits>

// Dims: B=8, L=2048, T=1024, Dh=1024, Dg=768, Dp=256
// Pipeline: Wqbf,Wkbf=cast(W)[+rowsum zero]; [HT,Hbf]=transpose+cast(H);
//           {Q,K}=proj (merged); Sexp=exp(Q@K^T/16)[+rowsum]; Z=(Sexp@HT^T)/rowsum
// R16: launch consolidation (7->5 nodes). sgemm/pv/transp = R15 measured-best.
// Workspace (u16): Qbf 2M | Kbf 4M | HT 16M | S 16M | Hbf 16M | Wqbf | Wkbf | rowsum f32

typedef float    f32x4  __attribute__((ext_vector_type(4)));
typedef __bf16   bf16x8 __attribute__((ext_vector_type(8)));
typedef unsigned short u16x8 __attribute__((ext_vector_type(8)));

__device__ __forceinline__ unsigned short f2bf(float f) {
    union { __bf16 b; unsigned short u; } c;
    c.b = (__bf16)f;                       // native RNE cvt
    return c.u;
}
__device__ __forceinline__ float bf2f(unsigned short u) {
    union { unsigned u; float f; } x; x.u = ((unsigned)u) << 16;
    return x.f;
}
__device__ __forceinline__ void gload_lds16(const unsigned short* g, unsigned short* l) {
    __builtin_amdgcn_global_load_lds(
        (const __attribute__((address_space(1))) void*)g,
        (__attribute__((address_space(3))) void*)l, 16, 0, 0);
}

// ---------------- cast Wq,Wk to bf16 + zero rowsum (one launch) ----------------
__global__ __launch_bounds__(256) void kn_castw(const float* __restrict__ Wq,
                                                const float* __restrict__ Wk,
                                                unsigned short* __restrict__ Wqbf,
                                                unsigned short* __restrict__ Wkbf,
                                                float* __restrict__ rowsum,
                                                int nq8, int nk8, int nrs4) {
    int tid = threadIdx.x;
    if (blockIdx.x == 0) {                 // zero rowsum: nrs4 f32x4 words
        f32x4 z = {};
        for (int j = tid; j < nrs4; j += 256)
            *(f32x4*)(rowsum + (size_t)j * 4) = z;
    }
    int i = blockIdx.x * 256 + tid;
    const float* src;
    unsigned short* dst;
    int idx;
    if (i < nq8) { idx = i; src = Wq; dst = Wqbf; }
    else { idx = i - nq8; if (idx >= nk8) return; src = Wk; dst = Wkbf; }
    f32x4 a = *(const f32x4*)(src + (size_t)idx * 8);
    f32x4 b = *(const f32x4*)(src + (size_t)idx * 8 + 4);
    u16x8 o;
#pragma unroll
    for (int j = 0; j < 4; ++j) { o[j] = f2bf(a[j]); o[4 + j] = f2bf(b[j]); }
    *(u16x8*)(dst + (size_t)idx * 8) = o;
}

// ------ transpose + dual cast, vectorized (unchanged R15) ------
__global__ __launch_bounds__(256) void kn_transp(const float* __restrict__ H,
                                                 unsigned short* __restrict__ HT,
                                                 unsigned short* __restrict__ Hbf,
                                                 int L, int D) {
    __shared__ float tile[64][65];
    int b = blockIdx.z;
    const float* src = H + (size_t)b * L * D;
    unsigned short* dstT = HT + (size_t)b * L * D;
    unsigned short* dstN = Hbf + (size_t)b * L * D;
    int l0 = blockIdx.y * 64, d0 = blockIdx.x * 64;
    int rh = threadIdx.x >> 3;
    int c8 = (threadIdx.x & 7) * 8;

#pragma unroll
    for (int i = 0; i < 2; ++i) {
        int r = rh + i * 32;
        const float* p = &src[(size_t)(l0 + r) * D + d0 + c8];
        f32x4 v0 = *(const f32x4*)p;
        f32x4 v1 = *(const f32x4*)(p + 4);
        u16x8 o;
#pragma unroll
        for (int j = 0; j < 4; ++j) {
            o[j] = f2bf(v0[j]); o[4 + j] = f2bf(v1[j]);
            tile[r][c8 + j] = v0[j];
            tile[r][c8 + 4 + j] = v1[j];
        }
        *(u16x8*)&dstN[(size_t)(l0 + r) * D + d0 + c8] = o;
    }
    __syncthreads();
#pragma unroll
    for (int i = 0; i < 2; ++i) {
        int d = rh + i * 32;
        u16x8 o;
#pragma unroll
        for (int j = 0; j < 8; ++j) o[j] = f2bf(tile[c8 + j][d]);
        *(u16x8*)&dstT[(size_t)(d0 + d) * L + l0 + c8] = o;
    }
}

// -------- qproj body (R15 logic): Q = G @ Wqbf^T; 32x128 tile --------
__device__ __forceinline__ void qproj_body(char* smem_raw,
                                           const float* __restrict__ A,
                                           const unsigned short* __restrict__ B,
                                           unsigned short* __restrict__ C,
                                           int N, int K, int t) {
    unsigned short* sA = (unsigned short*)smem_raw;           // 32x64 u16
    unsigned short* sB = sA + 32 * 64;                        // 128x64 u16
    float* st = (float*)smem_raw;

    int tid = threadIdx.x;
    int by = t >> 1;
    int bx = t & 1;
    const float* Ab = A + (size_t)by * 32 * K;
    const unsigned short* Bb = B + (size_t)bx * 128 * K;

    int lane = tid & 63;
    int wid = tid >> 6;
    int lr = lane & 15;
    int lg = lane >> 4;
    int xoff = (lane & 7) << 3;

    f32x4 acc[2][2] = {};

    for (int k0 = 0; k0 < K; k0 += 64) {
#pragma unroll
        for (int c = 0; c < 4; ++c) {
            int ch = c * 256 + tid;
            int row = ch >> 3;
            int g8 = (ch & 7) ^ (row & 7);
            gload_lds16(Bb + (size_t)row * K + k0 + g8 * 8, sB + ch * 8);
        }
        {
            int ch = tid;
            int row = ch >> 3;
            const float* srcp = Ab + (size_t)row * K + k0 + (ch & 7) * 8;
            f32x4 v0 = *(const f32x4*)srcp;
            f32x4 v1 = *(const f32x4*)(srcp + 4);
            u16x8 o;
#pragma unroll
            for (int j = 0; j < 4; ++j) { o[j] = f2bf(v0[j]); o[4 + j] = f2bf(v1[j]); }
            int sl = (ch & 7) ^ (row & 7);
            *(u16x8*)&sA[row * 64 + sl * 8] = o;
        }
        __syncthreads();
#pragma unroll
        for (int kk = 0; kk < 2; ++kk) {
            int kb = (kk * 32 + lg * 8) ^ xoff;
            bf16x8 af[2], bfr[2];
#pragma unroll
            for (int m = 0; m < 2; ++m)
                af[m] = *(const bf16x8*)&sA[(m * 16 + lr) * 64 + kb];
#pragma unroll
            for (int n = 0; n < 2; ++n)
                bfr[n] = *(const bf16x8*)&sB[(wid * 32 + n * 16 + lr) * 64 + kb];
#pragma unroll
            for (int m = 0; m < 2; ++m)
#pragma unroll
                for (int n = 0; n < 2; ++n)
                    acc[m][n] = __builtin_amdgcn_mfma_f32_16x16x32_bf16(af[m], bfr[n], acc[m][n], 0, 0, 0);
        }
        __syncthreads();
    }

#pragma unroll
    for (int m = 0; m < 2; ++m) {
        int r0 = m * 16 + lg * 4;
#pragma unroll
        for (int n = 0; n < 2; ++n) {
            int c0 = wid * 32 + n * 16 + lr;
#pragma unroll
            for (int j = 0; j < 4; ++j)
                st[(r0 + j) * 132 + c0] = acc[m][n][j];
        }
    }
    __syncthreads();
    int r  = tid >> 3;
    int c0 = (tid & 7) * 16;
    size_t grow = (size_t)(by * 32 + r) * N + bx * 128 + c0;
#pragma unroll
    for (int g = 0; g < 2; ++g) {
        f32x4 a = *(const f32x4*)&st[r * 132 + c0 + g * 8];
        f32x4 b = *(const f32x4*)&st[r * 132 + c0 + g * 8 + 4];
        u16x8 o;
#pragma unroll
        for (int j = 0; j < 4; ++j) { o[j] = f2bf(a[j]); o[4 + j] = f2bf(b[j]); }
        *(u16x8*)&C[grow + g * 8] = o;
    }
}

// -------- kproj body (R15 logic): K = Hbf @ Wkbf^T; 64x128 tile, all-bf16 --------
__device__ __forceinline__ void kproj_body(char* smem_raw,
                                           const unsigned short* __restrict__ A,
                                           const unsigned short* __restrict__ B,
                                           unsigned short* __restrict__ C,
                                           int N, int K, int t) {
    unsigned short* sA = (unsigned short*)smem_raw;           // 64x64 u16 = 8KB
    unsigned short* sB = sA + 64 * 64;                        // 128x64 u16 = 16KB
    float* st = (float*)smem_raw;

    int tid = threadIdx.x;
    int by = t >> 1;
    int bx = t & 1;
    const unsigned short* Ab = A + (size_t)by * 64 * K;
    const unsigned short* Bb = B + (size_t)bx * 128 * K;

    int lane = tid & 63;
    int wid = tid >> 6;
    int wr = wid >> 1, wc = wid & 1;
    int lr = lane & 15;
    int lg = lane >> 4;
    int xoff = (lane & 7) << 3;

    f32x4 acc[2][4] = {};

    for (int k0 = 0; k0 < K; k0 += 64) {
#pragma unroll
        for (int c = 0; c < 2; ++c) {
            int ch = c * 256 + tid;
            int row = ch >> 3;
            int g8 = (ch & 7) ^ (row & 7);
            gload_lds16(Ab + (size_t)row * K + k0 + g8 * 8, sA + ch * 8);
        }
#pragma unroll
        for (int c = 0; c < 4; ++c) {
            int ch = c * 256 + tid;
            int row = ch >> 3;
            int g8 = (ch & 7) ^ (row & 7);
            gload_lds16(Bb + (size_t)row * K + k0 + g8 * 8, sB + ch * 8);
        }
        __syncthreads();
#pragma unroll
        for (int kk = 0; kk < 2; ++kk) {
            int kb = (kk * 32 + lg * 8) ^ xoff;
            bf16x8 af[2], bfr[4];
#pragma unroll
            for (int m = 0; m < 2; ++m)
                af[m] = *(const bf16x8*)&sA[(wr * 32 + m * 16 + lr) * 64 + kb];
#pragma unroll
            for (int n = 0; n < 4; ++n)
                bfr[n] = *(const bf16x8*)&sB[(wc * 64 + n * 16 + lr) * 64 + kb];
#pragma unroll
            for (int m = 0; m < 2; ++m)
#pragma unroll
                for (int n = 0; n < 4; ++n)
                    acc[m][n] = __builtin_amdgcn_mfma_f32_16x16x32_bf16(af[m], bfr[n], acc[m][n], 0, 0, 0);
        }
        __syncthreads();
    }

#pragma unroll
    for (int m = 0; m < 2; ++m) {
        int r0 = wr * 32 + m * 16 + lg * 4;
#pragma unroll
        for (int n = 0; n < 4; ++n) {
            int c0 = wc * 64 + n * 16 + lr;
#pragma unroll
            for (int j = 0; j < 4; ++j)
                st[(r0 + j) * 132 + c0] = acc[m][n][j];
        }
    }
    __syncthreads();
    int r  = tid >> 2;
    int c0 = (tid & 3) * 32;
    size_t grow = (size_t)(by * 64 + r) * N + bx * 128 + c0;
#pragma unroll
    for (int g = 0; g < 4; ++g) {
        f32x4 a = *(const f32x4*)&st[r * 132 + c0 + g * 8];
        f32x4 b = *(const f32x4*)&st[r * 132 + c0 + g * 8 + 4];
        u16x8 o;
#pragma unroll
        for (int j = 0; j < 4; ++j) { o[j] = f2bf(a[j]); o[4 + j] = f2bf(b[j]); }
        *(u16x8*)&C[grow + g * 8] = o;
    }
}

// -------- merged projections: blocks [0,512) = kproj, [512,1024) = qproj --------
__global__ __launch_bounds__(256) void kn_proj(const unsigned short* __restrict__ Hbf,
                                               const unsigned short* __restrict__ Wkbf,
                                               unsigned short* __restrict__ Kbf,
                                               const float* __restrict__ G,
                                               const unsigned short* __restrict__ Wqbf,
                                               unsigned short* __restrict__ Qbf,
                                               int Dp, int Dh, int Dg) {
    __shared__ __align__(16) char smem_raw[64 * 132 * 4];    // max(kproj, qproj) needs
    int wg = blockIdx.x;
    if (wg < 512) kproj_body(smem_raw, Hbf, Wkbf, Kbf, Dp, Dh, wg);
    else          qproj_body(smem_raw, G, Wqbf, Qbf, Dp, Dg, wg - 512);
}

// ------- S-GEMM (unchanged R15): 256x128, BK=64, 8 waves; exp + rowsum epilogue -------
__global__ __launch_bounds__(512) void kn_sgemm(const unsigned short* __restrict__ A,
                                                const unsigned short* __restrict__ B,
                                                unsigned short* __restrict__ C,
                                                float* __restrict__ rowsum,
                                                int N, int K, int Trows,
                                                long batchA, long batchB, long batchC,
                                                float scale, int gxs) {
    __shared__ __align__(16) char smem_raw[49152];
    unsigned short* base = (unsigned short*)smem_raw;
    float* st = (float*)smem_raw;

    int tid = threadIdx.x;
    int wg = blockIdx.x;
    int bz = wg & 7;
    int t = wg >> 3;
    int by = t >> gxs;
    int bx = t & ((1 << gxs) - 1);

    const unsigned short* Ab = A + (size_t)bz * batchA + (size_t)by * 256 * K;
    const unsigned short* Bb = B + (size_t)bz * batchB + (size_t)bx * 128 * K;
    unsigned short* Cb = C + (size_t)bz * batchC;
    float* rs = rowsum + (size_t)bz * Trows;

    int lane = tid & 63;
    int wid = tid >> 6;
    int wr = wid >> 1, wc = wid & 1;
    int lr = lane & 15;
    int lg = lane >> 4;
    int xoff = (lane & 7) << 3;

    f32x4 acc[4][4] = {};

    for (int k0 = 0; k0 < K; k0 += 64) {
#pragma unroll
        for (int c = 0; c < 6; ++c) {
            int ch = c * 512 + tid;
            if (ch < 2048) {
                int row = ch >> 3;
                int g8 = (ch & 7) ^ (row & 7);
                gload_lds16(Ab + (size_t)row * K + k0 + g8 * 8, base + ch * 8);
            } else {
                int bc = ch - 2048;
                int row = bc >> 3;
                int g8 = (bc & 7) ^ (row & 7);
                gload_lds16(Bb + (size_t)row * K + k0 + g8 * 8, base + 16384 + bc * 8);
            }
        }
        __syncthreads();
#pragma unroll
        for (int kk = 0; kk < 2; ++kk) {
            int kb = (kk * 32 + lg * 8) ^ xoff;
            bf16x8 af[4], bfr[4];
#pragma unroll
            for (int m = 0; m < 4; ++m)
                af[m] = *(const bf16x8*)&base[(wr * 64 + m * 16 + lr) * 64 + kb];
#pragma unroll
            for (int n = 0; n < 4; ++n)
                bfr[n] = *(const bf16x8*)&base[16384 + (wc * 64 + n * 16 + lr) * 64 + kb];
#pragma unroll
            for (int m = 0; m < 4; ++m)
#pragma unroll
                for (int n = 0; n < 4; ++n)
                    acc[m][n] = __builtin_amdgcn_mfma_f32_16x16x32_bf16(af[m], bfr[n], acc[m][n], 0, 0, 0);
        }
        __syncthreads();
    }

#pragma unroll
    for (int q = 0; q < 4; ++q) {
        if (wr == q) {
#pragma unroll
            for (int m = 0; m < 4; ++m) {
                int rl = m * 16 + lg * 4;
#pragma unroll
                for (int n = 0; n < 4; ++n) {
                    int col = wc * 64 + n * 16 + lr;
#pragma unroll
                    for (int j = 0; j < 4; ++j)
                        st[(rl + j) * 132 + col] = acc[m][n][j] * scale;
                }
            }
        }
        __syncthreads();
        int r = tid >> 3;
        int c0 = (tid & 7) * 16;
        int grow_r = by * 256 + q * 64 + r;
        size_t grow = (size_t)grow_r * N + bx * 128 + c0;
        float psum = 0.f;
#pragma unroll
        for (int g = 0; g < 2; ++g) {
            f32x4 a = *(const f32x4*)&st[r * 132 + c0 + g * 8];
            f32x4 b = *(const f32x4*)&st[r * 132 + c0 + g * 8 + 4];
            u16x8 o;
#pragma unroll
            for (int j = 0; j < 4; ++j) {
                o[j]     = f2bf(__expf(a[j]));
                o[4 + j] = f2bf(__expf(b[j]));
                psum += bf2f(o[j]) + bf2f(o[4 + j]);
            }
            *(u16x8*)&Cb[grow + g * 8] = o;
        }
        psum += __shfl_xor(psum, 1);
        psum += __shfl_xor(psum, 2);
        psum += __shfl_xor(psum, 4);
        if ((tid & 7) == 0)
            atomicAdd(&rs[grow_r], psum);
        __syncthreads();
    }
}

// ------- PV (unchanged R10/R15 best): 256x128, BK=64, 3-buf, reg-dbuf frags -------
__global__ __launch_bounds__(512) void kn_pv(const unsigned short* __restrict__ A,
                                             const unsigned short* __restrict__ B,
                                             float* __restrict__ C,
                                             const float* __restrict__ rowsum,
                                             int N, int K, int Trows,
                                             long batchA, long batchB, long batchC,
                                             int gxs) {
    __shared__ __align__(16) char smem_raw[3 * 49152];       // 144KB
    unsigned short* base = (unsigned short*)smem_raw;
    float* st = (float*)smem_raw;

    int tid = threadIdx.x;
    int wg = blockIdx.x;
    int bz = wg & 7;
    int t = wg >> 3;
    int by = t >> gxs;
    int bx = t & ((1 << gxs) - 1);

    const unsigned short* Ab = A + (size_t)bz * batchA + (size_t)by * 256 * K;
    const unsigned short* Bb = B + (size_t)bz * batchB + (size_t)bx * 128 * K;
    float* Cb = C + (size_t)bz * batchC;
    const float* rs = rowsum + (size_t)bz * Trows;

    int lane = tid & 63;
    int wid = tid >> 6;
    int wr = wid >> 1, wc = wid & 1;
    int lr = lane & 15;
    int lg = lane >> 4;
    int xoff = (lane & 7) << 3;

    f32x4 acc[4][4] = {};
    bf16x8 fA0[4], fB0[4], fA1[4], fB1[4];

    auto STAGE_HALF = [&](int buf, int k0, int half) {
        unsigned short* dA = base + buf * 24576;
        unsigned short* dB = dA + 16384;
#pragma unroll
        for (int c = 0; c < 3; ++c) {
            int ch = half * 1536 + c * 512 + tid;
            if (ch < 2048) {
                int row = ch >> 3;
                int g8 = (ch & 7) ^ (row & 7);
                gload_lds16(Ab + (size_t)row * K + k0 + g8 * 8, dA + ch * 8);
            } else {
                int bc = ch - 2048;
                int row = bc >> 3;
                int g8 = (bc & 7) ^ (row & 7);
                gload_lds16(Bb + (size_t)row * K + k0 + g8 * 8, dB + bc * 8);
            }
        }
    };
    auto LDFRAG = [&](int buf, int kk, bf16x8* fa, bf16x8* fb) {
        unsigned short* pA = base + buf * 24576;
        unsigned short* pB = pA + 16384;
        int kb = (kk * 32 + lg * 8) ^ xoff;
#pragma unroll
        for (int m = 0; m < 4; ++m)
            fa[m] = *(const bf16x8*)&pA[(wr * 64 + m * 16 + lr) * 64 + kb];
#pragma unroll
        for (int n = 0; n < 4; ++n)
            fb[n] = *(const bf16x8*)&pB[(wc * 64 + n * 16 + lr) * 64 + kb];
    };

    int nt = K / 64;                           // 32
    STAGE_HALF(0, 0, 0);   STAGE_HALF(0, 0, 1);
    STAGE_HALF(1, 64, 0);  STAGE_HALF(1, 64, 1);
    asm volatile("s_waitcnt vmcnt(6)" ::: "memory");
    __builtin_amdgcn_s_barrier();
    LDFRAG(0, 0, fA0, fB0);

    int cur = 0;
    for (int tt = 0; tt < nt; ++tt) {
        int nb  = (cur >= 1) ? cur - 1 : 2;
        int nxt = (cur == 2) ? 0 : cur + 1;
        if (tt + 2 < nt) STAGE_HALF(nb, (tt + 2) * 64, 0);
        LDFRAG(cur, 1, fA1, fB1);
        __builtin_amdgcn_sched_barrier(0);
        __builtin_amdgcn_s_setprio(1);
#pragma unroll
        for (int m = 0; m < 4; ++m)
#pragma unroll
            for (int n = 0; n < 4; ++n)
                acc[m][n] = __builtin_amdgcn_mfma_f32_16x16x32_bf16(fA0[m], fB0[n], acc[m][n], 0, 0, 0);
        __builtin_amdgcn_s_setprio(0);
        __builtin_amdgcn_sched_barrier(0);
        if (tt + 2 < nt) STAGE_HALF(nb, (tt + 2) * 64, 1);
        __builtin_amdgcn_sched_barrier(0);
        __builtin_amdgcn_s_setprio(1);
#pragma unroll
        for (int m = 0; m < 4; ++m)
#pragma unroll
            for (int n = 0; n < 4; ++n)
                acc[m][n] = __builtin_amdgcn_mfma_f32_16x16x32_bf16(fA1[m], fB1[n], acc[m][n], 0, 0, 0);
        __builtin_amdgcn_s_setprio(0);
        __builtin_amdgcn_sched_barrier(0);
        if (tt + 1 < nt) {
            if (tt + 2 < nt) asm volatile("s_waitcnt vmcnt(6)" ::: "memory");
            else             asm volatile("s_waitcnt vmcnt(0)" ::: "memory");
            LDFRAG(nxt, 0, fA0, fB0);
            __builtin_amdgcn_sched_barrier(0);
            __builtin_amdgcn_s_barrier();
        }
        cur = nxt;
    }
    __syncthreads();

#pragma unroll
    for (int q = 0; q < 4; ++q) {
        if (wr == q) {
#pragma unroll
            for (int m = 0; m < 4; ++m) {
                int rl = m * 16 + lg * 4;
#pragma unroll
                for (int n = 0; n < 4; ++n) {
                    int col = wc * 64 + n * 16 + lr;
#pragma unroll
                    for (int j = 0; j < 4; ++j)
                        st[(rl + j) * 132 + col] = acc[m][n][j];
                }
            }
        }
        __syncthreads();
        int r = tid >> 3;
        int c0 = (tid & 7) * 16;
        float inv = 1.0f / rs[by * 256 + q * 64 + r];
        size_t grow = (size_t)(by * 256 + q * 64 + r) * N + bx * 128 + c0;
#pragma unroll
        for (int g = 0; g < 4; ++g) {
            f32x4 v = *(const f32x4*)&st[r * 132 + c0 + g * 4];
#pragma unroll
            for (int j = 0; j < 4; ++j) v[j] *= inv;
            *(f32x4*)&Cb[grow + g * 4] = v;
        }
        __syncthreads();
    }
}

extern "C" void kernel_launch(void* const* d_in, const int* in_sizes, int n_in,
                              void* d_out, int out_size, void* d_ws, size_t ws_size,
                              hipStream_t stream) {
    constexpr int B = 8, L = 2048, T = 1024, Dh = 1024, Dg = 768, Dp = 256;
    const float* H  = (const float*)d_in[0];
    const float* G  = (const float*)d_in[1];
    const float* Wq = (const float*)d_in[2];
    const float* Wk = (const float*)d_in[3];
    float* Z = (float*)d_out;

    unsigned short* Qbf  = (unsigned short*)d_ws;            // B*T*Dp  = 2M
    unsigned short* Kbf  = Qbf + (size_t)B * T * Dp;         // B*L*Dp  = 4M
    unsigned short* HT   = Kbf + (size_t)B * L * Dp;         // B*Dh*L  = 16M
    unsigned short* S    = HT  + (size_t)B * Dh * L;         // B*T*L   = 16M
    unsigned short* Hbf  = S   + (size_t)B * T * L;          // B*L*Dh  = 16M
    unsigned short* Wqbf = Hbf + (size_t)B * L * Dh;         // Dp*Dg
    unsigned short* Wkbf = Wqbf + (size_t)Dp * Dg;           // Dp*Dh
    float* rowsum = (float*)(Wkbf + (size_t)Dp * Dh);        // B*T f32

    // 1. cast Wq,Wk + zero rowsum
    int nq8 = Dp * Dg / 8, nk8 = Dp * Dh / 8;
    kn_castw<<<(nq8 + nk8 + 255) / 256, 256, 0, stream>>>
        (Wq, Wk, Wqbf, Wkbf, rowsum, nq8, nk8, B * T / 4);

    // 2. HT + Hbf from H
    kn_transp<<<dim3(Dh / 64, L / 64, B), dim3(256), 0, stream>>>(H, HT, Hbf, L, Dh);

    // 3. merged projections: 512 kproj blocks + 512 qproj blocks
    kn_proj<<<1024, 256, 0, stream>>>(Hbf, Wkbf, Kbf, G, Wqbf, Qbf, Dp, Dh, Dg);

    // 4. Sexp = exp(Q@K^T/16) + rowsum
    kn_sgemm<<<(T / 256) * (L / 128) * B, 512, 0, stream>>>
        (Qbf, Kbf, S, rowsum, L, Dp, T, (long)T * Dp, (long)L * Dp, (long)T * L, 0.0625f, 4);

    // 5. Z = (Sexp @ HT^T)/rowsum
    kn_pv<<<(T / 256) * (Dh / 128) * B, 512, 0, stream>>>
        (S, HT, Z, rowsum, Dh, L, T, (long)T * L, (long)Dh * L, (long)T * Dh, 3);
}

// Round 17
// 119.319 us; speedup vs baseline: 1.2888x; 1.0406x over previous
//
#include <hip/hip_runtime.h>
#include <hip/hip_bf16.h>
#include <type_traits>

// Dims: B=8, L=2048, T=1024, Dh=1024, Dg=768, Dp=256
// Pipeline: [HT,Hbf]=transpose+cast(H) [+castW +rowsum-zero fused];
//           {Q,K}=proj (merged); Sexp=exp(Q@K^T/16)[+rowsum]; Z=(Sexp@HT^T)/rowsum
// R17: PV reverted to R7's measured-best simple 2-buf prefetch loop (49.1 us);
//      castw folded into transp (5->4 dispatches). sgemm/proj = R16.
// Workspace (u16): Qbf 2M | Kbf 4M | HT 16M | S 16M | Hbf 16M | Wqbf | Wkbf | rowsum f32

typedef float    f32x4  __attribute__((ext_vector_type(4)));
typedef __bf16   bf16x8 __attribute__((ext_vector_type(8)));
typedef unsigned short u16x8 __attribute__((ext_vector_type(8)));

__device__ __forceinline__ unsigned short f2bf(float f) {
    union { __bf16 b; unsigned short u; } c;
    c.b = (__bf16)f;                       // native RNE cvt
    return c.u;
}
__device__ __forceinline__ float bf2f(unsigned short u) {
    union { unsigned u; float f; } x; x.u = ((unsigned)u) << 16;
    return x.f;
}
__device__ __forceinline__ void gload_lds16(const unsigned short* g, unsigned short* l) {
    __builtin_amdgcn_global_load_lds(
        (const __attribute__((address_space(1))) void*)g,
        (__attribute__((address_space(3))) void*)l, 16, 0, 0);
}

// ---- transpose + dual cast (R15) + fused W-cast / rowsum-zero on low blocks ----
__global__ __launch_bounds__(256) void kn_transp(const float* __restrict__ H,
                                                 unsigned short* __restrict__ HT,
                                                 unsigned short* __restrict__ Hbf,
                                                 const float* __restrict__ Wq,
                                                 const float* __restrict__ Wk,
                                                 unsigned short* __restrict__ Wqbf,
                                                 unsigned short* __restrict__ Wkbf,
                                                 float* __restrict__ rowsum,
                                                 int L, int D, int nq8, int nk8, int nrs4) {
    __shared__ float tile[64][65];
    int b = blockIdx.z;
    const float* src = H + (size_t)b * L * D;
    unsigned short* dstT = HT + (size_t)b * L * D;
    unsigned short* dstN = Hbf + (size_t)b * L * D;
    int l0 = blockIdx.y * 64, d0 = blockIdx.x * 64;
    int rh = threadIdx.x >> 3;
    int c8 = (threadIdx.x & 7) * 8;

    // ---- fused side-work on flattened block id ----
    int fid = blockIdx.x + gridDim.x * (blockIdx.y + gridDim.y * blockIdx.z);
    if (fid == 0) {                        // zero rowsum (8KB)
        f32x4 z = {};
        for (int j = threadIdx.x; j < nrs4; j += 256)
            *(f32x4*)(rowsum + (size_t)j * 4) = z;
    }
    {
        int i = fid * 256 + threadIdx.x;   // W-cast: chunks [0, nq8+nk8)
        if (i < nq8 + nk8) {
            const float* s;
            unsigned short* dp;
            int idx;
            if (i < nq8) { idx = i; s = Wq; dp = Wqbf; }
            else         { idx = i - nq8; s = Wk; dp = Wkbf; }
            f32x4 a = *(const f32x4*)(s + (size_t)idx * 8);
            f32x4 bb = *(const f32x4*)(s + (size_t)idx * 8 + 4);
            u16x8 o;
#pragma unroll
            for (int j = 0; j < 4; ++j) { o[j] = f2bf(a[j]); o[4 + j] = f2bf(bb[j]); }
            *(u16x8*)(dp + (size_t)idx * 8) = o;
        }
    }

    // ---- main transpose work ----
#pragma unroll
    for (int i = 0; i < 2; ++i) {
        int r = rh + i * 32;
        const float* p = &src[(size_t)(l0 + r) * D + d0 + c8];
        f32x4 v0 = *(const f32x4*)p;
        f32x4 v1 = *(const f32x4*)(p + 4);
        u16x8 o;
#pragma unroll
        for (int j = 0; j < 4; ++j) {
            o[j] = f2bf(v0[j]); o[4 + j] = f2bf(v1[j]);
            tile[r][c8 + j] = v0[j];
            tile[r][c8 + 4 + j] = v1[j];
        }
        *(u16x8*)&dstN[(size_t)(l0 + r) * D + d0 + c8] = o;
    }
    __syncthreads();
#pragma unroll
    for (int i = 0; i < 2; ++i) {
        int d = rh + i * 32;
        u16x8 o;
#pragma unroll
        for (int j = 0; j < 8; ++j) o[j] = f2bf(tile[c8 + j][d]);
        *(u16x8*)&dstT[(size_t)(d0 + d) * L + l0 + c8] = o;
    }
}

// -------- qproj body (unchanged R16) --------
__device__ __forceinline__ void qproj_body(char* smem_raw,
                                           const float* __restrict__ A,
                                           const unsigned short* __restrict__ B,
                                           unsigned short* __restrict__ C,
                                           int N, int K, int t) {
    unsigned short* sA = (unsigned short*)smem_raw;
    unsigned short* sB = sA + 32 * 64;
    float* st = (float*)smem_raw;

    int tid = threadIdx.x;
    int by = t >> 1;
    int bx = t & 1;
    const float* Ab = A + (size_t)by * 32 * K;
    const unsigned short* Bb = B + (size_t)bx * 128 * K;

    int lane = tid & 63;
    int wid = tid >> 6;
    int lr = lane & 15;
    int lg = lane >> 4;
    int xoff = (lane & 7) << 3;

    f32x4 acc[2][2] = {};

    for (int k0 = 0; k0 < K; k0 += 64) {
#pragma unroll
        for (int c = 0; c < 4; ++c) {
            int ch = c * 256 + tid;
            int row = ch >> 3;
            int g8 = (ch & 7) ^ (row & 7);
            gload_lds16(Bb + (size_t)row * K + k0 + g8 * 8, sB + ch * 8);
        }
        {
            int ch = tid;
            int row = ch >> 3;
            const float* srcp = Ab + (size_t)row * K + k0 + (ch & 7) * 8;
            f32x4 v0 = *(const f32x4*)srcp;
            f32x4 v1 = *(const f32x4*)(srcp + 4);
            u16x8 o;
#pragma unroll
            for (int j = 0; j < 4; ++j) { o[j] = f2bf(v0[j]); o[4 + j] = f2bf(v1[j]); }
            int sl = (ch & 7) ^ (row & 7);
            *(u16x8*)&sA[row * 64 + sl * 8] = o;
        }
        __syncthreads();
#pragma unroll
        for (int kk = 0; kk < 2; ++kk) {
            int kb = (kk * 32 + lg * 8) ^ xoff;
            bf16x8 af[2], bfr[2];
#pragma unroll
            for (int m = 0; m < 2; ++m)
                af[m] = *(const bf16x8*)&sA[(m * 16 + lr) * 64 + kb];
#pragma unroll
            for (int n = 0; n < 2; ++n)
                bfr[n] = *(const bf16x8*)&sB[(wid * 32 + n * 16 + lr) * 64 + kb];
#pragma unroll
            for (int m = 0; m < 2; ++m)
#pragma unroll
                for (int n = 0; n < 2; ++n)
                    acc[m][n] = __builtin_amdgcn_mfma_f32_16x16x32_bf16(af[m], bfr[n], acc[m][n], 0, 0, 0);
        }
        __syncthreads();
    }

#pragma unroll
    for (int m = 0; m < 2; ++m) {
        int r0 = m * 16 + lg * 4;
#pragma unroll
        for (int n = 0; n < 2; ++n) {
            int c0 = wid * 32 + n * 16 + lr;
#pragma unroll
            for (int j = 0; j < 4; ++j)
                st[(r0 + j) * 132 + c0] = acc[m][n][j];
        }
    }
    __syncthreads();
    int r  = tid >> 3;
    int c0 = (tid & 7) * 16;
    size_t grow = (size_t)(by * 32 + r) * N + bx * 128 + c0;
#pragma unroll
    for (int g = 0; g < 2; ++g) {
        f32x4 a = *(const f32x4*)&st[r * 132 + c0 + g * 8];
        f32x4 b = *(const f32x4*)&st[r * 132 + c0 + g * 8 + 4];
        u16x8 o;
#pragma unroll
        for (int j = 0; j < 4; ++j) { o[j] = f2bf(a[j]); o[4 + j] = f2bf(b[j]); }
        *(u16x8*)&C[grow + g * 8] = o;
    }
}

// -------- kproj body (unchanged R16) --------
__device__ __forceinline__ void kproj_body(char* smem_raw,
                                           const unsigned short* __restrict__ A,
                                           const unsigned short* __restrict__ B,
                                           unsigned short* __restrict__ C,
                                           int N, int K, int t) {
    unsigned short* sA = (unsigned short*)smem_raw;
    unsigned short* sB = sA + 64 * 64;
    float* st = (float*)smem_raw;

    int tid = threadIdx.x;
    int by = t >> 1;
    int bx = t & 1;
    const unsigned short* Ab = A + (size_t)by * 64 * K;
    const unsigned short* Bb = B + (size_t)bx * 128 * K;

    int lane = tid & 63;
    int wid = tid >> 6;
    int wr = wid >> 1, wc = wid & 1;
    int lr = lane & 15;
    int lg = lane >> 4;
    int xoff = (lane & 7) << 3;

    f32x4 acc[2][4] = {};

    for (int k0 = 0; k0 < K; k0 += 64) {
#pragma unroll
        for (int c = 0; c < 2; ++c) {
            int ch = c * 256 + tid;
            int row = ch >> 3;
            int g8 = (ch & 7) ^ (row & 7);
            gload_lds16(Ab + (size_t)row * K + k0 + g8 * 8, sA + ch * 8);
        }
#pragma unroll
        for (int c = 0; c < 4; ++c) {
            int ch = c * 256 + tid;
            int row = ch >> 3;
            int g8 = (ch & 7) ^ (row & 7);
            gload_lds16(Bb + (size_t)row * K + k0 + g8 * 8, sB + ch * 8);
        }
        __syncthreads();
#pragma unroll
        for (int kk = 0; kk < 2; ++kk) {
            int kb = (kk * 32 + lg * 8) ^ xoff;
            bf16x8 af[2], bfr[4];
#pragma unroll
            for (int m = 0; m < 2; ++m)
                af[m] = *(const bf16x8*)&sA[(wr * 32 + m * 16 + lr) * 64 + kb];
#pragma unroll
            for (int n = 0; n < 4; ++n)
                bfr[n] = *(const bf16x8*)&sB[(wc * 64 + n * 16 + lr) * 64 + kb];
#pragma unroll
            for (int m = 0; m < 2; ++m)
#pragma unroll
                for (int n = 0; n < 4; ++n)
                    acc[m][n] = __builtin_amdgcn_mfma_f32_16x16x32_bf16(af[m], bfr[n], acc[m][n], 0, 0, 0);
        }
        __syncthreads();
    }

#pragma unroll
    for (int m = 0; m < 2; ++m) {
        int r0 = wr * 32 + m * 16 + lg * 4;
#pragma unroll
        for (int n = 0; n < 4; ++n) {
            int c0 = wc * 64 + n * 16 + lr;
#pragma unroll
            for (int j = 0; j < 4; ++j)
                st[(r0 + j) * 132 + c0] = acc[m][n][j];
        }
    }
    __syncthreads();
    int r  = tid >> 2;
    int c0 = (tid & 3) * 32;
    size_t grow = (size_t)(by * 64 + r) * N + bx * 128 + c0;
#pragma unroll
    for (int g = 0; g < 4; ++g) {
        f32x4 a = *(const f32x4*)&st[r * 132 + c0 + g * 8];
        f32x4 b = *(const f32x4*)&st[r * 132 + c0 + g * 8 + 4];
        u16x8 o;
#pragma unroll
        for (int j = 0; j < 4; ++j) { o[j] = f2bf(a[j]); o[4 + j] = f2bf(b[j]); }
        *(u16x8*)&C[grow + g * 8] = o;
    }
}

__global__ __launch_bounds__(256) void kn_proj(const unsigned short* __restrict__ Hbf,
                                               const unsigned short* __restrict__ Wkbf,
                                               unsigned short* __restrict__ Kbf,
                                               const float* __restrict__ G,
                                               const unsigned short* __restrict__ Wqbf,
                                               unsigned short* __restrict__ Qbf,
                                               int Dp, int Dh, int Dg) {
    __shared__ __align__(16) char smem_raw[64 * 132 * 4];
    int wg = blockIdx.x;
    if (wg < 512) kproj_body(smem_raw, Hbf, Wkbf, Kbf, Dp, Dh, wg);
    else          qproj_body(smem_raw, G, Wqbf, Qbf, Dp, Dg, wg - 512);
}

// ------- S-GEMM (unchanged R16): 256x128, BK=64, 8 waves; exp + rowsum epilogue -------
__global__ __launch_bounds__(512) void kn_sgemm(const unsigned short* __restrict__ A,
                                                const unsigned short* __restrict__ B,
                                                unsigned short* __restrict__ C,
                                                float* __restrict__ rowsum,
                                                int N, int K, int Trows,
                                                long batchA, long batchB, long batchC,
                                                float scale, int gxs) {
    __shared__ __align__(16) char smem_raw[49152];
    unsigned short* base = (unsigned short*)smem_raw;
    float* st = (float*)smem_raw;

    int tid = threadIdx.x;
    int wg = blockIdx.x;
    int bz = wg & 7;
    int t = wg >> 3;
    int by = t >> gxs;
    int bx = t & ((1 << gxs) - 1);

    const unsigned short* Ab = A + (size_t)bz * batchA + (size_t)by * 256 * K;
    const unsigned short* Bb = B + (size_t)bz * batchB + (size_t)bx * 128 * K;
    unsigned short* Cb = C + (size_t)bz * batchC;
    float* rs = rowsum + (size_t)bz * Trows;

    int lane = tid & 63;
    int wid = tid >> 6;
    int wr = wid >> 1, wc = wid & 1;
    int lr = lane & 15;
    int lg = lane >> 4;
    int xoff = (lane & 7) << 3;

    f32x4 acc[4][4] = {};

    for (int k0 = 0; k0 < K; k0 += 64) {
#pragma unroll
        for (int c = 0; c < 6; ++c) {
            int ch = c * 512 + tid;
            if (ch < 2048) {
                int row = ch >> 3;
                int g8 = (ch & 7) ^ (row & 7);
                gload_lds16(Ab + (size_t)row * K + k0 + g8 * 8, base + ch * 8);
            } else {
                int bc = ch - 2048;
                int row = bc >> 3;
                int g8 = (bc & 7) ^ (row & 7);
                gload_lds16(Bb + (size_t)row * K + k0 + g8 * 8, base + 16384 + bc * 8);
            }
        }
        __syncthreads();
#pragma unroll
        for (int kk = 0; kk < 2; ++kk) {
            int kb = (kk * 32 + lg * 8) ^ xoff;
            bf16x8 af[4], bfr[4];
#pragma unroll
            for (int m = 0; m < 4; ++m)
                af[m] = *(const bf16x8*)&base[(wr * 64 + m * 16 + lr) * 64 + kb];
#pragma unroll
            for (int n = 0; n < 4; ++n)
                bfr[n] = *(const bf16x8*)&base[16384 + (wc * 64 + n * 16 + lr) * 64 + kb];
#pragma unroll
            for (int m = 0; m < 4; ++m)
#pragma unroll
                for (int n = 0; n < 4; ++n)
                    acc[m][n] = __builtin_amdgcn_mfma_f32_16x16x32_bf16(af[m], bfr[n], acc[m][n], 0, 0, 0);
        }
        __syncthreads();
    }

#pragma unroll
    for (int q = 0; q < 4; ++q) {
        if (wr == q) {
#pragma unroll
            for (int m = 0; m < 4; ++m) {
                int rl = m * 16 + lg * 4;
#pragma unroll
                for (int n = 0; n < 4; ++n) {
                    int col = wc * 64 + n * 16 + lr;
#pragma unroll
                    for (int j = 0; j < 4; ++j)
                        st[(rl + j) * 132 + col] = acc[m][n][j] * scale;
                }
            }
        }
        __syncthreads();
        int r = tid >> 3;
        int c0 = (tid & 7) * 16;
        int grow_r = by * 256 + q * 64 + r;
        size_t grow = (size_t)grow_r * N + bx * 128 + c0;
        float psum = 0.f;
#pragma unroll
        for (int g = 0; g < 2; ++g) {
            f32x4 a = *(const f32x4*)&st[r * 132 + c0 + g * 8];
            f32x4 b = *(const f32x4*)&st[r * 132 + c0 + g * 8 + 4];
            u16x8 o;
#pragma unroll
            for (int j = 0; j < 4; ++j) {
                o[j]     = f2bf(__expf(a[j]));
                o[4 + j] = f2bf(__expf(b[j]));
                psum += bf2f(o[j]) + bf2f(o[4 + j]);
            }
            *(u16x8*)&Cb[grow + g * 8] = o;
        }
        psum += __shfl_xor(psum, 1);
        psum += __shfl_xor(psum, 2);
        psum += __shfl_xor(psum, 4);
        if ((tid & 7) == 0)
            atomicAdd(&rs[grow_r], psum);
        __syncthreads();
    }
}

// ------- PV: R7's measured-best simple structure — 256x128, BK=64, 8 waves,
//         2-buf LDS (96KB), STAGE(t+1)-before-COMPUTE(t), 1 syncthreads/tile.
//         Epilogue divides by rowsum. -------
__global__ __launch_bounds__(512) void kn_pv(const unsigned short* __restrict__ A,
                                             const unsigned short* __restrict__ B,
                                             float* __restrict__ C,
                                             const float* __restrict__ rowsum,
                                             int N, int K, int Trows,
                                             long batchA, long batchB, long batchC,
                                             int gxs) {
    __shared__ __align__(16) char smem_raw[2 * 49152];       // 96KB: 2 bufs (A32+B16)
    unsigned short* base = (unsigned short*)smem_raw;
    float* st = (float*)smem_raw;

    int tid = threadIdx.x;
    int wg = blockIdx.x;
    int bz = wg & 7;
    int t = wg >> 3;
    int by = t >> gxs;
    int bx = t & ((1 << gxs) - 1);

    const unsigned short* Ab = A + (size_t)bz * batchA + (size_t)by * 256 * K;
    const unsigned short* Bb = B + (size_t)bz * batchB + (size_t)bx * 128 * K;
    float* Cb = C + (size_t)bz * batchC;
    const float* rs = rowsum + (size_t)bz * Trows;

    int lane = tid & 63;
    int wid = tid >> 6;
    int wr = wid >> 1, wc = wid & 1;
    int lr = lane & 15;
    int lg = lane >> 4;
    int xoff = (lane & 7) << 3;

    f32x4 acc[4][4] = {};

    auto STAGE = [&](int buf, int k0) {
        unsigned short* dA = base + buf * 24576;
        unsigned short* dB = dA + 16384;
#pragma unroll
        for (int c = 0; c < 6; ++c) {
            int ch = c * 512 + tid;
            if (ch < 2048) {
                int row = ch >> 3;
                int g8 = (ch & 7) ^ (row & 7);
                gload_lds16(Ab + (size_t)row * K + k0 + g8 * 8, dA + ch * 8);
            } else {
                int bc = ch - 2048;
                int row = bc >> 3;
                int g8 = (bc & 7) ^ (row & 7);
                gload_lds16(Bb + (size_t)row * K + k0 + g8 * 8, dB + bc * 8);
            }
        }
    };
    auto COMPUTE = [&](int buf) {
        unsigned short* pA = base + buf * 24576;
        unsigned short* pB = pA + 16384;
#pragma unroll
        for (int kk = 0; kk < 2; ++kk) {
            int kb = (kk * 32 + lg * 8) ^ xoff;
            bf16x8 af[4], bfr[4];
#pragma unroll
            for (int m = 0; m < 4; ++m)
                af[m] = *(const bf16x8*)&pA[(wr * 64 + m * 16 + lr) * 64 + kb];
#pragma unroll
            for (int n = 0; n < 4; ++n)
                bfr[n] = *(const bf16x8*)&pB[(wc * 64 + n * 16 + lr) * 64 + kb];
#pragma unroll
            for (int m = 0; m < 4; ++m)
#pragma unroll
                for (int n = 0; n < 4; ++n)
                    acc[m][n] = __builtin_amdgcn_mfma_f32_16x16x32_bf16(af[m], bfr[n], acc[m][n], 0, 0, 0);
        }
    };

    int nt = K / 64;                           // 32
    STAGE(0, 0);
    __syncthreads();
    int cur = 0;
    for (int tt = 0; tt < nt; ++tt) {
        if (tt + 1 < nt) STAGE(cur ^ 1, (tt + 1) * 64);  // prefetch overlaps compute
        COMPUTE(cur);
        __syncthreads();                                 // drains vmcnt, fences bufs
        cur ^= 1;
    }

    // epilogue: 4 quarters via st[64][132], divide by rowsum
#pragma unroll
    for (int q = 0; q < 4; ++q) {
        if (wr == q) {
#pragma unroll
            for (int m = 0; m < 4; ++m) {
                int rl = m * 16 + lg * 4;
#pragma unroll
                for (int n = 0; n < 4; ++n) {
                    int col = wc * 64 + n * 16 + lr;
#pragma unroll
                    for (int j = 0; j < 4; ++j)
                        st[(rl + j) * 132 + col] = acc[m][n][j];
                }
            }
        }
        __syncthreads();
        int r = tid >> 3;
        int c0 = (tid & 7) * 16;
        float inv = 1.0f / rs[by * 256 + q * 64 + r];
        size_t grow = (size_t)(by * 256 + q * 64 + r) * N + bx * 128 + c0;
#pragma unroll
        for (int g = 0; g < 4; ++g) {
            f32x4 v = *(const f32x4*)&st[r * 132 + c0 + g * 4];
#pragma unroll
            for (int j = 0; j < 4; ++j) v[j] *= inv;
            *(f32x4*)&Cb[grow + g * 4] = v;
        }
        __syncthreads();
    }
}

extern "C" void kernel_launch(void* const* d_in, const int* in_sizes, int n_in,
                              void* d_out, int out_size, void* d_ws, size_t ws_size,
                              hipStream_t stream) {
    constexpr int B = 8, L = 2048, T = 1024, Dh = 1024, Dg = 768, Dp = 256;
    const float* H  = (const float*)d_in[0];
    const float* G  = (const float*)d_in[1];
    const float* Wq = (const float*)d_in[2];
    const float* Wk = (const float*)d_in[3];
    float* Z = (float*)d_out;

    unsigned short* Qbf  = (unsigned short*)d_ws;            // B*T*Dp  = 2M
    unsigned short* Kbf  = Qbf + (size_t)B * T * Dp;         // B*L*Dp  = 4M
    unsigned short* HT   = Kbf + (size_t)B * L * Dp;         // B*Dh*L  = 16M
    unsigned short* S    = HT  + (size_t)B * Dh * L;         // B*T*L   = 16M
    unsigned short* Hbf  = S   + (size_t)B * T * L;          // B*L*Dh  = 16M
    unsigned short* Wqbf = Hbf + (size_t)B * L * Dh;         // Dp*Dg
    unsigned short* Wkbf = Wqbf + (size_t)Dp * Dg;           // Dp*Dh
    float* rowsum = (float*)(Wkbf + (size_t)Dp * Dh);        // B*T f32

    int nq8 = Dp * Dg / 8, nk8 = Dp * Dh / 8;

    // 1. HT + Hbf from H, with W-cast + rowsum-zero fused onto low blocks
    kn_transp<<<dim3(Dh / 64, L / 64, B), dim3(256), 0, stream>>>
        (H, HT, Hbf, Wq, Wk, Wqbf, Wkbf, rowsum, L, Dh, nq8, nk8, B * T / 4);

    // 2. merged projections: 512 kproj blocks + 512 qproj blocks
    kn_proj<<<1024, 256, 0, stream>>>(Hbf, Wkbf, Kbf, G, Wqbf, Qbf, Dp, Dh, Dg);

    // 3. Sexp = exp(Q@K^T/16) + rowsum
    kn_sgemm<<<(T / 256) * (L / 128) * B, 512, 0, stream>>>
        (Qbf, Kbf, S, rowsum, L, Dp, T, (long)T * Dp, (long)L * Dp, (long)T * L, 0.0625f, 4);

    // 4. Z = (Sexp @ HT^T)/rowsum
    kn_pv<<<(T / 256) * (Dh / 128) * B, 512, 0, stream>>>
        (S, HT, Z, rowsum, Dh, L, T, (long)T * L, (long)Dh * L, (long)T * Dh, 3);
}